// Round 9
// baseline (137.702 us; speedup 1.0000x reference)
//
#include <hip/hip_runtime.h>
#include <hip/hip_bf16.h>
#include <math.h>

typedef __attribute__((ext_vector_type(8))) short short8;
typedef __attribute__((ext_vector_type(4))) float f32x4;
typedef __attribute__((ext_vector_type(4))) unsigned int uint4v;

constexpr int Hm = 512, Lm = 1024, Bm = 8;
constexpr int PAR = Hm * 64;
constexpr size_t PLANE = (size_t)Bm * Hm * Lm;   // 4194304 ushorts per plane

static __device__ __forceinline__ unsigned short f2bf(float f) {
    __hip_bfloat16 h = __float2bfloat16(f);
    return *reinterpret_cast<unsigned short*>(&h);
}
static __device__ __forceinline__ float bf2f(unsigned short u) {
    return __uint_as_float((unsigned)u << 16);
}
static __device__ __forceinline__ uint2 pack4(const unsigned short* x) {
    return make_uint2((unsigned)x[0] | ((unsigned)x[1] << 16),
                      (unsigned)x[2] | ((unsigned)x[3] << 16));
}

// par planes: 0 rr, 1 ri, 2 wr, 3 wi, 4 r64r, 5 r64i
__global__ void k0_params(const float* __restrict__ log_dt,
                          const float* __restrict__ log_A_real,
                          const float* __restrict__ A_imag,
                          const float* __restrict__ B_real,
                          const float* __restrict__ B_imag,
                          const float* __restrict__ C_real,
                          const float* __restrict__ C_imag,
                          float* __restrict__ par) {
    int idx = blockIdx.x * blockDim.x + threadIdx.x;
    if (idx >= PAR) return;
    int h = idx >> 6;
    double dt = exp((double)log_dt[h]);
    double Ar = -exp((double)log_A_real[idx]);
    double Ai = (double)A_imag[idx];
    double ar = Ar * dt, ai = Ai * dt;          // dtA
    double er = exp(ar);
    double rr = er * cos(ai), ri = er * sin(ai);        // r
    double nr = rr - 1.0, ni = ri;
    double den = Ar * Ar + Ai * Ai;
    double qr = (nr * Ar + ni * Ai) / den;
    double qi = (ni * Ar - nr * Ai) / den;
    double Br = (double)B_real[idx], Bi = (double)B_imag[idx];
    double bbr = qr * Br - qi * Bi, bbi = qr * Bi + qi * Br;
    double Cr = (double)C_real[idx], Ci = (double)C_imag[idx];
    double wr = Cr * bbr - Ci * bbi, wi = Cr * bbi + Ci * bbr;
    double e64 = exp(ar * 64.0);
    double p64 = ai * 64.0;
    par[0 * PAR + idx] = (float)rr;
    par[1 * PAR + idx] = (float)ri;
    par[2 * PAR + idx] = (float)wr;
    par[3 * PAR + idx] = (float)wi;
    par[4 * PAR + idx] = (float)(e64 * cos(p64));
    par[5 * PAR + idx] = (float)(e64 * sin(p64));
}

// conv_w f32 -> hi/lo bf16 planes
__global__ void k_cvt(const float* __restrict__ w,
                      unsigned short* __restrict__ oh,
                      unsigned short* __restrict__ ol) {
    int i = (blockIdx.x * 256 + threadIdx.x) * 4;
    float4 v = *(const float4*)&w[i];
    unsigned short h0 = f2bf(v.x), h1 = f2bf(v.y), h2 = f2bf(v.z), h3 = f2bf(v.w);
    unsigned short l0 = f2bf(v.x - bf2f(h0));
    unsigned short l1 = f2bf(v.y - bf2f(h1));
    unsigned short l2 = f2bf(v.z - bf2f(h2));
    unsigned short l3 = f2bf(v.w - bf2f(h3));
    *(uint2*)&oh[i] = make_uint2((unsigned)h0 | ((unsigned)h1 << 16),
                                 (unsigned)h2 | ((unsigned)h3 << 16));
    *(uint2*)&ol[i] = make_uint2((unsigned)l0 | ((unsigned)l1 << 16),
                                 (unsigned)l2 | ((unsigned)l3 << 16));
}

// K generator: K[h][j] = Re(sum_n w_n r_n^j), j in [0,1024). Output: per h,
// packed dwords [plane(2)][rep(4)][550]: rep s element pair (2d,2d+1) =
// bf16 hi/lo of K[2d+s], K[2d+1+s] (zeros past 1023). 4400 dwords per h.
__global__ __launch_bounds__(256) void k_kgen(const float* __restrict__ par,
                                              unsigned int* __restrict__ Krep) {
    __shared__ __align__(16) char smem[20992];   // kl 4x4224 | Kf 4096
    const int tid = threadIdx.x, lane = tid & 63, wid = tid >> 6;
    float* kl = (float*)smem + wid * 1056;       // [16][66] per wave
    float* Kf = (float*)(smem + 16896);          // [1024]
    const int h = blockIdx.x;
    const int pidx = h * 64 + lane;
    const float rrf = par[0 * PAR + pidx], rif = par[1 * PAR + pidx];
    float pr = par[2 * PAR + pidx], pi = par[3 * PAR + pidx];   // w
    float br = par[4 * PAR + pidx], bi = par[5 * PAR + pidx];   // r^64
    int cc = wid * 4;
    while (cc) {   // p = w * (r^64)^(4*wid)
        if (cc & 1) { float t_ = pr * br - pi * bi; pi = fmaf(pr, bi, pi * br); pr = t_; }
        float t2 = br * br - bi * bi; bi = 2.f * br * bi; br = t2;
        cc >>= 1;
    }
    const int jj = lane & 15, nq = lane >> 4;
    for (int q = 0; q < 16; ++q) {
        #pragma unroll
        for (int j = 0; j < 16; ++j) {
            kl[j * 66 + lane] = pr;
            float t_ = pr * rrf - pi * rif; pi = fmaf(pr, rif, pi * rrf); pr = t_;
        }
        asm volatile("s_waitcnt lgkmcnt(0)" ::: "memory");
        float s0 = 0.f, s1 = 0.f;
        #pragma unroll
        for (int n = 0; n < 16; n += 4) {
            float2 a = *(const float2*)&kl[jj * 66 + nq * 16 + n];
            float2 b2 = *(const float2*)&kl[jj * 66 + nq * 16 + n + 2];
            s0 += a.x + a.y; s1 += b2.x + b2.y;
        }
        float s = s0 + s1;
        s += __shfl_xor(s, 16);
        s += __shfl_xor(s, 32);
        if (lane < 16) Kf[wid * 256 + q * 16 + jj] = s;
        asm volatile("s_waitcnt lgkmcnt(0)" ::: "memory");
    }
    __syncthreads();
    // pack: hi/lo planes, 4 shifted replicas, dword-packed
    for (int t = tid; t < 4400; t += 256) {
        int p = t / 2200;
        int rem = t - p * 2200;
        int s = rem / 550;
        int d = rem - s * 550;
        int idx0 = 2 * d + s;
        float k0 = (idx0 < 1024) ? Kf[idx0] : 0.f;
        float k1 = (idx0 + 1 < 1024) ? Kf[idx0 + 1] : 0.f;
        unsigned short h0 = f2bf(k0), h1 = f2bf(k1);
        unsigned short v0, v1;
        if (p == 0) { v0 = h0; v1 = h1; }
        else { v0 = f2bf(k0 - bf2f(h0)); v1 = f2bf(k1 - bf2f(h1)); }
        Krep[(size_t)h * 4400 + t] = (unsigned)v0 | ((unsigned)v1 << 16);
    }
}

// Toeplitz block-conv via MFMA. One block per h (8 waves); wave w owns output
// chunk pair (w, 15-w). y_i(64x8) = sum_d T_d @ u_{i-d}; N=16 = 2 chunks x 8 b.
// A[t'][k] = G[1023-64d-t'+k], G[idx] = K[idx] (zeros past 1023); G pre-split
// hi/lo + 4 shifted replicas loaded straight from Krep (b64-aligned reads).
// LDS 38080 B: GH [0,8800) GL [8800,17600) uh [17600,38080).
__global__ __launch_bounds__(512, 8) void k_tconv(const float* __restrict__ u,
                                                  const float* __restrict__ Dvec,
                                                  const unsigned int* __restrict__ Krep,
                                                  const float* __restrict__ Dummy,
                                                  unsigned short* __restrict__ YbfH) {
    __shared__ __align__(16) char smem[38080];
    unsigned short* GH = (unsigned short*)smem;            // [4 rep][1100]
    unsigned short* GL = (unsigned short*)(smem + 8800);
    unsigned short* uh = (unsigned short*)(smem + 17600);  // [16jc][2ks][8b][40]

    const int tid = threadIdx.x, lane = tid & 63, wid = tid >> 6;   // 8 waves
    const int h = blockIdx.x;
    const int fr = lane & 15, fq = lane >> 4;
    const short8 z8 = {};

    // ---- load pre-built G replicas ----
    {
        const uint4* src = (const uint4*)(Krep + (size_t)h * 4400);
        uint4* dst = (uint4*)smem;
        #pragma unroll
        for (int o = tid; o < 1100; o += 512) dst[o] = src[o];
    }
    // ---- stage u -> bf16 B-operand layout ----
    {
        const int b = tid >> 6, t64 = tid & 63;
        const float* ub = u + ((size_t)(b * 512 + h)) * 1024;
        #pragma unroll
        for (int g = 0; g < 4; ++g) {
            int s = t64 * 4 + g * 256;
            float4 v = *(const float4*)&ub[s];
            unsigned short t0 = f2bf(v.x), t1 = f2bf(v.y), t2 = f2bf(v.z), t3 = f2bf(v.w);
            int jc = s >> 6, ks = (s >> 5) & 1, k0 = s & 31;
            int off = ((jc * 2 + ks) * 8 + b) * 40 + k0;
            *(uint2*)&uh[off] = make_uint2((unsigned)t0 | ((unsigned)t1 << 16),
                                           (unsigned)t2 | ((unsigned)t3 << 16));
        }
    }
    __syncthreads();

    const float Dh = Dvec[h];
    const int i_lo = wid;
    const int i_hi = 15 - wid;
    f32x4 acc[4] = {};

    // per-lane replica + 8B-aligned base: G index = 1023-fr+8fq+32-16W+e
    const int sA = (3 - fr) & 3;
    const unsigned short* gh0 = GH + sA * 1100 + (1023 - fr - sA) + fq * 8 + 32;
    const unsigned short* gl0 = GL + sA * 1100 + (1023 - fr - sA) + fq * 8 + 32;

    short8 Fh[8], Fl[8];
#define LOADW(W) { \
    const uint2* ph_ = (const uint2*)(gh0 - 16 * (W)); \
    const uint2* pl_ = (const uint2*)(gl0 - 16 * (W)); \
    uint2 a_ = ph_[0], b_ = ph_[1]; \
    uint2 c_ = pl_[0], d_ = pl_[1]; \
    uint4v th_ = { a_.x, a_.y, b_.x, b_.y }; \
    uint4v tl_ = { c_.x, c_.y, d_.x, d_.y }; \
    Fh[(W) & 7] = __builtin_bit_cast(short8, th_); \
    Fl[(W) & 7] = __builtin_bit_cast(short8, tl_); }

    LOADW(0); LOADW(1); LOADW(2); LOADW(3); LOADW(4); LOADW(5);

    // ---- d-loop: prefetch ring (W = 4d+mf-2ks+2), no barriers ----
    #pragma unroll
    for (int d = 0; d < 16; ++d) {
        if (d <= i_hi) {
            if (d < i_hi) { LOADW(4 * d + 6); LOADW(4 * d + 7); }
            {   // ks = 1 (W = 4d+mf)
                int jm = ((fr >> 3) ? i_hi : i_lo) - d;
                bool vv = jm >= 0;
                int ja = vv ? jm : 0;
                int uoff = ((ja * 2 + 1) * 8 + (fr & 7)) * 40 + fq * 8;
                short8 bh = *(const short8*)&uh[uoff];
                if (!vv) bh = z8;
                #pragma unroll
                for (int mf = 0; mf < 4; ++mf) {
                    const int sl = (4 * d + mf) & 7;
                    acc[mf] = __builtin_amdgcn_mfma_f32_16x16x32_bf16(Fh[sl], bh, acc[mf], 0, 0, 0);
                    acc[mf] = __builtin_amdgcn_mfma_f32_16x16x32_bf16(Fl[sl], bh, acc[mf], 0, 0, 0);
                }
            }
            if (d < i_hi) { LOADW(4 * d + 8); LOADW(4 * d + 9); }
            {   // ks = 0 (W = 4d+mf+2)
                int jm = ((fr >> 3) ? i_hi : i_lo) - d;
                bool vv = jm >= 0;
                int ja = vv ? jm : 0;
                int uoff = ((ja * 2 + 0) * 8 + (fr & 7)) * 40 + fq * 8;
                short8 bh = *(const short8*)&uh[uoff];
                if (!vv) bh = z8;
                #pragma unroll
                for (int mf = 0; mf < 4; ++mf) {
                    const int sl = (4 * d + mf + 2) & 7;
                    acc[mf] = __builtin_amdgcn_mfma_f32_16x16x32_bf16(Fh[sl], bh, acc[mf], 0, 0, 0);
                    acc[mf] = __builtin_amdgcn_mfma_f32_16x16x32_bf16(Fl[sl], bh, acc[mf], 0, 0, 0);
                }
            }
        }
    }
#undef LOADW

    // ---- epilogue: y + D*u, gelu, hi-plane write ----
    const int i_mine = (fr >> 3) ? i_hi : i_lo;
    const int bb = fr & 7;
    unsigned short* dsth = YbfH + ((size_t)(bb * 512 + h)) * 1024 + i_mine * 64;
    #pragma unroll
    for (int mf = 0; mf < 4; ++mf) {
        unsigned short oh[4];
        #pragma unroll
        for (int j = 0; j < 4; ++j) {
            int tp = mf * 16 + fq * 4 + j;
            int uoff = ((i_mine * 2 + (tp >> 5)) * 8 + bb) * 40 + (tp & 31);
            float uv = bf2f(uh[uoff]);
            float y = acc[mf][j] + Dh * uv;
            float g = 0.5f * y * (1.0f + erff(y * 0.70710678118654752f));
            oh[j] = f2bf(g);
        }
        *(uint2*)&dsth[mf * 16 + fq * 4] = pack4(oh);
    }
}

// transpose [b][c][l] -> [b][l][c] (hi plane only)
__global__ __launch_bounds__(256) void k_tr(const unsigned short* __restrict__ Ybf,
                                            unsigned short* __restrict__ Ytb) {
    __shared__ unsigned short tl[64][72];
    const int t = threadIdx.x;
    const int b = blockIdx.z;
    const int c0 = blockIdx.y * 64, l0 = blockIdx.x * 64;
    {
        const int c = t >> 2, lq = (t & 3) * 16;
        const unsigned short* src = Ybf + ((size_t)(b * 512 + c0 + c)) * 1024 + l0 + lq;
        uint4 v0 = *(const uint4*)src;
        uint4 v1 = *(const uint4*)(src + 8);
        *(uint4*)&tl[c][lq] = v0;
        *(uint4*)&tl[c][lq + 8] = v1;
    }
    __syncthreads();
    {
        const int l = t >> 2, cq = (t & 3) * 16;
        unsigned int o[8];
        #pragma unroll
        for (int k = 0; k < 8; ++k)
            o[k] = (unsigned)tl[cq + 2 * k][l] | ((unsigned)tl[cq + 2 * k + 1][l] << 16);
        unsigned short* dst = Ytb + ((size_t)(b * 1024 + l0 + l)) * 512 + c0 + cq;
        *(uint4*)dst = *(uint4*)&o[0];
        *(uint4*)(dst + 8) = *(uint4*)&o[4];
    }
}

// split-W bf16 MFMA GEMM (Wh*Yh + Wl*Yh) + bias/GLU/pool/dec epilogue
__global__ __launch_bounds__(256) void k2_gemm(const unsigned short* __restrict__ WbfH,
                                               const unsigned short* __restrict__ WbfL,
                                               const unsigned short* __restrict__ Ytb,
                                               const float* __restrict__ conv_b,
                                               const float* __restrict__ dec_w,
                                               float* __restrict__ partial) {
    __shared__ unsigned short WTh[128][40], WTl[128][40];
    __shared__ unsigned short YTh[128][40];
    __shared__ float red[4][64][20];
    const int tid = threadIdx.x, lane = tid & 63, wid = tid >> 6;
    const int b = blockIdx.z, oblk = blockIdx.y, lblk = blockIdx.x;
    const int o0 = oblk * 64, l0 = lblk * 128;
    const int fr = lane & 15, fq = lane >> 4;

    f32x4 acc[8][2] = {};

    const int srow = tid >> 1, skh = (tid & 1) * 16;
    const int grow = (srow < 64) ? (o0 + srow) : (512 + o0 + srow - 64);
    const size_t woff = (size_t)grow * 512 + skh;
    const size_t yoff = ((size_t)(b * 1024) + l0 + srow) * 512 + skh;

    for (int c0 = 0; c0 < 512; c0 += 32) {
        __syncthreads();
        uint4 wh0 = *(const uint4*)(WbfH + woff + c0);
        uint4 wh1 = *(const uint4*)(WbfH + woff + c0 + 8);
        uint4 wl0 = *(const uint4*)(WbfL + woff + c0);
        uint4 wl1 = *(const uint4*)(WbfL + woff + c0 + 8);
        uint4 yh0 = *(const uint4*)(Ytb + yoff + c0);
        uint4 yh1 = *(const uint4*)(Ytb + yoff + c0 + 8);
        *(uint4*)&WTh[srow][skh]     = wh0;
        *(uint4*)&WTh[srow][skh + 8] = wh1;
        *(uint4*)&WTl[srow][skh]     = wl0;
        *(uint4*)&WTl[srow][skh + 8] = wl1;
        *(uint4*)&YTh[srow][skh]     = yh0;
        *(uint4*)&YTh[srow][skh + 8] = yh1;
        __syncthreads();
        short8 b0h = *(const short8*)&YTh[wid * 32 + fr][fq * 8];
        short8 b1h = *(const short8*)&YTh[wid * 32 + 16 + fr][fq * 8];
        #pragma unroll
        for (int mf = 0; mf < 8; ++mf) {
            short8 ah = *(const short8*)&WTh[mf * 16 + fr][fq * 8];
            short8 al = *(const short8*)&WTl[mf * 16 + fr][fq * 8];
            acc[mf][0] = __builtin_amdgcn_mfma_f32_16x16x32_bf16(ah, b0h, acc[mf][0], 0, 0, 0);
            acc[mf][1] = __builtin_amdgcn_mfma_f32_16x16x32_bf16(ah, b1h, acc[mf][1], 0, 0, 0);
            acc[mf][0] = __builtin_amdgcn_mfma_f32_16x16x32_bf16(al, b0h, acc[mf][0], 0, 0, 0);
            acc[mf][1] = __builtin_amdgcn_mfma_f32_16x16x32_bf16(al, b1h, acc[mf][1], 0, 0, 0);
        }
    }

    #pragma unroll
    for (int mf = 0; mf < 4; ++mf)
        #pragma unroll
        for (int j = 0; j < 4; ++j) {
            int ol = mf * 16 + fq * 4 + j;
            float ba = conv_b[o0 + ol];
            float bb = conv_b[512 + o0 + ol];
            float s = 0.f;
            #pragma unroll
            for (int nf = 0; nf < 2; ++nf) {
                float za = acc[mf][nf][j] + ba;
                float zb = acc[mf + 4][nf][j] + bb;
                s += za / (1.f + expf(-zb));
            }
            red[wid][ol][fr] = s;
        }
    __syncthreads();
    if (tid < 64) {
        float s = 0.f;
        #pragma unroll
        for (int w = 0; w < 4; ++w) {
            float4 r0 = *(const float4*)&red[w][tid][0];
            float4 r1 = *(const float4*)&red[w][tid][4];
            float4 r2 = *(const float4*)&red[w][tid][8];
            float4 r3 = *(const float4*)&red[w][tid][12];
            s += (r0.x + r0.y + r0.z + r0.w) + (r1.x + r1.y + r1.z + r1.w)
               + (r2.x + r2.y + r2.z + r2.w) + (r3.x + r3.y + r3.z + r3.w);
        }
        float val = s * dec_w[o0 + tid] * (1.0f / 1024.0f);
        #pragma unroll
        for (int off = 32; off; off >>= 1) val += __shfl_xor(val, off);
        if (tid == 0) partial[((b * 8) + oblk) * 8 + lblk] = val;
    }
}

__global__ void k3_final(const float* __restrict__ partial,
                         const float* __restrict__ dec_b,
                         float* __restrict__ out) {
    int b = threadIdx.x;
    if (b < Bm) {
        float s = dec_b[0];
        for (int i = 0; i < 64; ++i) s += partial[b * 64 + i];
        out[b] = s;
    }
}

extern "C" void kernel_launch(void* const* d_in, const int* in_sizes, int n_in,
                              void* d_out, int out_size, void* d_ws, size_t ws_size,
                              hipStream_t stream) {
    const float* u          = (const float*)d_in[0];
    const float* log_dt     = (const float*)d_in[1];
    const float* log_A_real = (const float*)d_in[2];
    const float* A_imag     = (const float*)d_in[3];
    const float* B_real     = (const float*)d_in[4];
    const float* B_imag     = (const float*)d_in[5];
    const float* C_real     = (const float*)d_in[6];
    const float* C_imag     = (const float*)d_in[7];
    const float* Dvec       = (const float*)d_in[8];
    const float* conv_w     = (const float*)d_in[9];
    const float* conv_b     = (const float*)d_in[10];
    const float* dec_w      = (const float*)d_in[11];
    const float* dec_b      = (const float*)d_in[12];

    char* base = (char*)d_ws;
    float* par           = (float*)base;                                // 768 KB
    unsigned int* Krep   = (unsigned int*)(base + 1048576);             // 9.0 MB
    unsigned short* YbfH = (unsigned short*)(base + 10485760);          // 8 MB
    unsigned short* Ytb  = (unsigned short*)(base + 18874368);          // 8 MB
    unsigned short* Wh   = (unsigned short*)(base + 27262976);          // 1 MB
    unsigned short* Wl   = (unsigned short*)(base + 28311552);          // 1 MB
    float* partial       = (float*)(base + 29360128);                   // 2 KB
    float* out           = (float*)d_out;

    k0_params<<<128, 256, 0, stream>>>(log_dt, log_A_real, A_imag, B_real,
                                       B_imag, C_real, C_imag, par);
    k_cvt<<<512, 256, 0, stream>>>(conv_w, Wh, Wl);
    k_kgen<<<512, 256, 0, stream>>>(par, Krep);
    k_tconv<<<512, 512, 0, stream>>>(u, Dvec, Krep, nullptr, YbfH);
    k_tr<<<dim3(16, 8, 8), 256, 0, stream>>>(YbfH, Ytb);
    k2_gemm<<<dim3(8, 8, 8), 256, 0, stream>>>(Wh, Wl, Ytb, conv_b, dec_w, partial);
    k3_final<<<1, 64, 0, stream>>>(partial, dec_b, out);
}

// Round 10
// 87.164 us; speedup vs baseline: 1.5798x; 1.5798x over previous
//
#include <hip/hip_runtime.h>
#include <hip/hip_bf16.h>
#include <math.h>

typedef __attribute__((ext_vector_type(8))) short short8;
typedef __attribute__((ext_vector_type(4))) float f32x4;
typedef __attribute__((ext_vector_type(16))) float f32x16;
typedef __attribute__((ext_vector_type(4))) unsigned int uint4v;

constexpr int Hm = 512, Lm = 1024, Bm = 8;
constexpr int PAR = Hm * 64;

static __device__ __forceinline__ unsigned short f2bf(float f) {
    __hip_bfloat16 h = __float2bfloat16(f);
    return *reinterpret_cast<unsigned short*>(&h);
}
static __device__ __forceinline__ float bf2f(unsigned short u) {
    return __uint_as_float((unsigned)u << 16);
}
static __device__ __forceinline__ uint2 pack4(const unsigned short* x) {
    return make_uint2((unsigned)x[0] | ((unsigned)x[1] << 16),
                      (unsigned)x[2] | ((unsigned)x[3] << 16));
}
static __device__ __forceinline__ short8 ld16u(const char* p) {   // 2 x b64
    uint2 a = *(const uint2*)p;
    uint2 b = *(const uint2*)(p + 8);
    uint4v t = { a.x, a.y, b.x, b.y };
    return __builtin_bit_cast(short8, t);
}

// par planes: 0 rr, 1 ri, 2 wr, 3 wi, 4 r64r, 5 r64i
__global__ void k0_params(const float* __restrict__ log_dt,
                          const float* __restrict__ log_A_real,
                          const float* __restrict__ A_imag,
                          const float* __restrict__ B_real,
                          const float* __restrict__ B_imag,
                          const float* __restrict__ C_real,
                          const float* __restrict__ C_imag,
                          float* __restrict__ par) {
    int idx = blockIdx.x * blockDim.x + threadIdx.x;
    if (idx >= PAR) return;
    int h = idx >> 6;
    double dt = exp((double)log_dt[h]);
    double Ar = -exp((double)log_A_real[idx]);
    double Ai = (double)A_imag[idx];
    double ar = Ar * dt, ai = Ai * dt;          // dtA
    double er = exp(ar);
    double rr = er * cos(ai), ri = er * sin(ai);        // r
    double nr = rr - 1.0, ni = ri;
    double den = Ar * Ar + Ai * Ai;
    double qr = (nr * Ar + ni * Ai) / den;
    double qi = (ni * Ar - nr * Ai) / den;
    double Br = (double)B_real[idx], Bi = (double)B_imag[idx];
    double bbr = qr * Br - qi * Bi, bbi = qr * Bi + qi * Br;
    double Cr = (double)C_real[idx], Ci = (double)C_imag[idx];
    double wr = Cr * bbr - Ci * bbi, wi = Cr * bbi + Ci * bbr;
    double e64 = exp(ar * 64.0);
    double p64 = ai * 64.0;
    par[0 * PAR + idx] = (float)rr;
    par[1 * PAR + idx] = (float)ri;
    par[2 * PAR + idx] = (float)wr;
    par[3 * PAR + idx] = (float)wi;
    par[4 * PAR + idx] = (float)(e64 * cos(p64));
    par[5 * PAR + idx] = (float)(e64 * sin(p64));
}

// conv_w f32 -> hi/lo bf16 planes
__global__ void k_cvt(const float* __restrict__ w,
                      unsigned short* __restrict__ oh,
                      unsigned short* __restrict__ ol) {
    int i = (blockIdx.x * 256 + threadIdx.x) * 4;
    float4 v = *(const float4*)&w[i];
    unsigned short h0 = f2bf(v.x), h1 = f2bf(v.y), h2 = f2bf(v.z), h3 = f2bf(v.w);
    unsigned short l0 = f2bf(v.x - bf2f(h0));
    unsigned short l1 = f2bf(v.y - bf2f(h1));
    unsigned short l2 = f2bf(v.z - bf2f(h2));
    unsigned short l3 = f2bf(v.w - bf2f(h3));
    *(uint2*)&oh[i] = make_uint2((unsigned)h0 | ((unsigned)h1 << 16),
                                 (unsigned)h2 | ((unsigned)h3 << 16));
    *(uint2*)&ol[i] = make_uint2((unsigned)l0 | ((unsigned)l1 << 16),
                                 (unsigned)l2 | ((unsigned)l3 << 16));
}

// K generator (R9-proven): per h, packed dwords [plane(2)][rep(4)][550]:
// rep s dword d = bf16 (plane) of (G[2d+s], G[2d+1+s]); G[j]=K[j], 0 past 1023.
__global__ __launch_bounds__(256) void k_kgen(const float* __restrict__ par,
                                              unsigned int* __restrict__ Krep) {
    __shared__ __align__(16) char smem[20992];   // kl 4x4224 | Kf 4096
    const int tid = threadIdx.x, lane = tid & 63, wid = tid >> 6;
    float* kl = (float*)smem + wid * 1056;       // [16][66] per wave
    float* Kf = (float*)(smem + 16896);          // [1024]
    const int h = blockIdx.x;
    const int pidx = h * 64 + lane;
    const float rrf = par[0 * PAR + pidx], rif = par[1 * PAR + pidx];
    float pr = par[2 * PAR + pidx], pi = par[3 * PAR + pidx];   // w
    float br = par[4 * PAR + pidx], bi = par[5 * PAR + pidx];   // r^64
    int cc = wid * 4;
    while (cc) {   // p = w * (r^64)^(4*wid)
        if (cc & 1) { float t_ = pr * br - pi * bi; pi = fmaf(pr, bi, pi * br); pr = t_; }
        float t2 = br * br - bi * bi; bi = 2.f * br * bi; br = t2;
        cc >>= 1;
    }
    const int jj = lane & 15, nq = lane >> 4;
    for (int q = 0; q < 16; ++q) {
        #pragma unroll
        for (int j = 0; j < 16; ++j) {
            kl[j * 66 + lane] = pr;
            float t_ = pr * rrf - pi * rif; pi = fmaf(pr, rif, pi * rrf); pr = t_;
        }
        asm volatile("s_waitcnt lgkmcnt(0)" ::: "memory");
        float s0 = 0.f, s1 = 0.f;
        #pragma unroll
        for (int n = 0; n < 16; n += 4) {
            float2 a = *(const float2*)&kl[jj * 66 + nq * 16 + n];
            float2 b2 = *(const float2*)&kl[jj * 66 + nq * 16 + n + 2];
            s0 += a.x + a.y; s1 += b2.x + b2.y;
        }
        float s = s0 + s1;
        s += __shfl_xor(s, 16);
        s += __shfl_xor(s, 32);
        if (lane < 16) Kf[wid * 256 + q * 16 + jj] = s;
        asm volatile("s_waitcnt lgkmcnt(0)" ::: "memory");
    }
    __syncthreads();
    for (int t = tid; t < 4400; t += 256) {
        int p = t / 2200;
        int rem = t - p * 2200;
        int s = rem / 550;
        int d = rem - s * 550;
        int idx0 = 2 * d + s;
        float k0 = (idx0 < 1024) ? Kf[idx0] : 0.f;
        float k1 = (idx0 + 1 < 1024) ? Kf[idx0 + 1] : 0.f;
        unsigned short h0 = f2bf(k0), h1 = f2bf(k1);
        unsigned short v0, v1;
        if (p == 0) { v0 = h0; v1 = h1; }
        else { v0 = f2bf(k0 - bf2f(h0)); v1 = f2bf(k1 - bf2f(h1)); }
        Krep[(size_t)h * 4400 + t] = (unsigned)v0 | ((unsigned)v1 << 16);
    }
}

// Toeplitz block-conv, 32x32x16 MFMA, 2-tile register blocking.
// One block per h, 2 waves (128 thr). Wave w owns 8 chunks as 2 N=32 tiles:
// tileA = {w, 7-w, 4+w, 3-w}, tileB = tileA+8.  N = 4 chunks x 8 batches.
// A[m][k16] = G[E - m + k16], E = 1023 - 64d - 32mf + 16ks; lane m=lane&31,
// k16 = 8*(lane>>5)+j.  Windows per d (E-offsets): {-32,-16,0,16,32,48}.
// LDS: G [0,17600) = [plane][rep4][1100 elem]; uh [17600,36032) = [16j][8b][72];
// zeros [36032,36160). Y bounce reuses G region after d-loop.
__global__ __launch_bounds__(128, 2) void k_tconv(const float* __restrict__ u,
                                                  const float* __restrict__ Dvec,
                                                  const unsigned int* __restrict__ Krep,
                                                  unsigned short* __restrict__ YbfH) {
    __shared__ __align__(16) char smem[36160];
    const int tid = threadIdx.x, lane = tid & 63, w = tid >> 6;
    const int h = blockIdx.x;
    const int m = lane & 31, q = lane >> 5;
    const int cg = (lane >> 3) & 3, b = lane & 7;

    // stage G (straight copy: k_kgen layout == LDS layout)
    {
        const uint4* src = (const uint4*)(Krep + (size_t)h * 4400);
        uint4* dst = (uint4*)smem;
        #pragma unroll
        for (int o = 0; o < 9; ++o) {
            int idx = tid + o * 128;
            if (idx < 1100) dst[idx] = src[idx];
        }
    }
    if (tid < 8) { uint4 z = {0, 0, 0, 0}; ((uint4*)(smem + 36032))[tid] = z; }
    // stage u -> [j][b][72] bf16
    {
        const int b2 = tid >> 4, e4 = (tid & 15) * 4;
        const float* ub = u + ((size_t)(b2 * 512 + h)) * 1024;
        #pragma unroll
        for (int j = 0; j < 16; ++j) {
            float4 v = *(const float4*)&ub[j * 64 + e4];
            unsigned short t0 = f2bf(v.x), t1 = f2bf(v.y), t2 = f2bf(v.z), t3 = f2bf(v.w);
            *(uint2*)(smem + 17600 + j * 1152 + b2 * 144 + e4 * 2) =
                make_uint2((unsigned)t0 | ((unsigned)t1 << 16),
                           (unsigned)t2 | ((unsigned)t3 << 16));
        }
    }
    __syncthreads();

    // chunk assignment
    const int iA = (cg & 2) ? ((cg & 1) ? 3 - w : 4 + w) : ((cg & 1) ? 7 - w : w);
    const int iB = iA + 8;
    const int tmaxA = 7 - w;
    const int dmax = 15 - w;

    // B-operand running addresses (bytes into smem)
    const int ub0 = 17600 + b * 144 + q * 16;
    int aA = ub0 + iA * 1152;
    int aB = ub0 + iB * 1152;
    const int zl = 36032 + q * 16;

    // A-operand base: plane p at p*8800; replica r at r*2200; elem e at 2e.
    // e(d, window -32) = 991 - m - r + 8q - 64d ; window offsets 0..160 bytes.
    const int r = (3 - m) & 3;
    int baseH = r * 2200 + (991 - m - r + 8 * q) * 2;
    int baseL = baseH + 8800;

    const f32x16 zacc = {};
    f32x16 acA0 = zacc, acA1 = zacc, acB0 = zacc, acB1 = zacc;

    for (int d = 0; d <= dmax; ++d) {
        const char* pH = smem + baseH;
        const char* pL = smem + baseL;
        short8 m2h = ld16u(pH +   0), m1h = ld16u(pH +  32);
        short8 w0h = ld16u(pH +  64), w1h = ld16u(pH +  96);
        short8 w2h = ld16u(pH + 128), w3h = ld16u(pH + 160);
        short8 m2l = ld16u(pL +   0), m1l = ld16u(pL +  32);
        short8 w0l = ld16u(pL +  64), w1l = ld16u(pL +  96);
        short8 w2l = ld16u(pL + 128), w3l = ld16u(pL + 160);

        if (d <= tmaxA) {   // tile A
            const char* pb = smem + ((d <= iA) ? aA : zl);
            short8 b0 = *(const short8*)(pb +  0);
            short8 b1 = *(const short8*)(pb + 32);
            short8 b2 = *(const short8*)(pb + 64);
            short8 b3 = *(const short8*)(pb + 96);
            acA0 = __builtin_amdgcn_mfma_f32_32x32x16_bf16(w0h, b0, acA0, 0, 0, 0);
            acA0 = __builtin_amdgcn_mfma_f32_32x32x16_bf16(w0l, b0, acA0, 0, 0, 0);
            acA1 = __builtin_amdgcn_mfma_f32_32x32x16_bf16(m2h, b0, acA1, 0, 0, 0);
            acA1 = __builtin_amdgcn_mfma_f32_32x32x16_bf16(m2l, b0, acA1, 0, 0, 0);
            acA0 = __builtin_amdgcn_mfma_f32_32x32x16_bf16(w1h, b1, acA0, 0, 0, 0);
            acA0 = __builtin_amdgcn_mfma_f32_32x32x16_bf16(w1l, b1, acA0, 0, 0, 0);
            acA1 = __builtin_amdgcn_mfma_f32_32x32x16_bf16(m1h, b1, acA1, 0, 0, 0);
            acA1 = __builtin_amdgcn_mfma_f32_32x32x16_bf16(m1l, b1, acA1, 0, 0, 0);
            acA0 = __builtin_amdgcn_mfma_f32_32x32x16_bf16(w2h, b2, acA0, 0, 0, 0);
            acA0 = __builtin_amdgcn_mfma_f32_32x32x16_bf16(w2l, b2, acA0, 0, 0, 0);
            acA1 = __builtin_amdgcn_mfma_f32_32x32x16_bf16(w0h, b2, acA1, 0, 0, 0);
            acA1 = __builtin_amdgcn_mfma_f32_32x32x16_bf16(w0l, b2, acA1, 0, 0, 0);
            acA0 = __builtin_amdgcn_mfma_f32_32x32x16_bf16(w3h, b3, acA0, 0, 0, 0);
            acA0 = __builtin_amdgcn_mfma_f32_32x32x16_bf16(w3l, b3, acA0, 0, 0, 0);
            acA1 = __builtin_amdgcn_mfma_f32_32x32x16_bf16(w1h, b3, acA1, 0, 0, 0);
            acA1 = __builtin_amdgcn_mfma_f32_32x32x16_bf16(w1l, b3, acA1, 0, 0, 0);
        }
        {   // tile B
            const char* pb = smem + ((d <= iB) ? aB : zl);
            short8 b0 = *(const short8*)(pb +  0);
            short8 b1 = *(const short8*)(pb + 32);
            short8 b2 = *(const short8*)(pb + 64);
            short8 b3 = *(const short8*)(pb + 96);
            acB0 = __builtin_amdgcn_mfma_f32_32x32x16_bf16(w0h, b0, acB0, 0, 0, 0);
            acB0 = __builtin_amdgcn_mfma_f32_32x32x16_bf16(w0l, b0, acB0, 0, 0, 0);
            acB1 = __builtin_amdgcn_mfma_f32_32x32x16_bf16(m2h, b0, acB1, 0, 0, 0);
            acB1 = __builtin_amdgcn_mfma_f32_32x32x16_bf16(m2l, b0, acB1, 0, 0, 0);
            acB0 = __builtin_amdgcn_mfma_f32_32x32x16_bf16(w1h, b1, acB0, 0, 0, 0);
            acB0 = __builtin_amdgcn_mfma_f32_32x32x16_bf16(w1l, b1, acB0, 0, 0, 0);
            acB1 = __builtin_amdgcn_mfma_f32_32x32x16_bf16(m1h, b1, acB1, 0, 0, 0);
            acB1 = __builtin_amdgcn_mfma_f32_32x32x16_bf16(m1l, b1, acB1, 0, 0, 0);
            acB0 = __builtin_amdgcn_mfma_f32_32x32x16_bf16(w2h, b2, acB0, 0, 0, 0);
            acB0 = __builtin_amdgcn_mfma_f32_32x32x16_bf16(w2l, b2, acB0, 0, 0, 0);
            acB1 = __builtin_amdgcn_mfma_f32_32x32x16_bf16(w0h, b2, acB1, 0, 0, 0);
            acB1 = __builtin_amdgcn_mfma_f32_32x32x16_bf16(w0l, b2, acB1, 0, 0, 0);
            acB0 = __builtin_amdgcn_mfma_f32_32x32x16_bf16(w3h, b3, acB0, 0, 0, 0);
            acB0 = __builtin_amdgcn_mfma_f32_32x32x16_bf16(w3l, b3, acB0, 0, 0, 0);
            acB1 = __builtin_amdgcn_mfma_f32_32x32x16_bf16(w1h, b3, acB1, 0, 0, 0);
            acB1 = __builtin_amdgcn_mfma_f32_32x32x16_bf16(w1l, b3, acB1, 0, 0, 0);
        }
        baseH -= 128; baseL -= 128; aA -= 1152; aB -= 1152;
    }

    const float Dh = Dvec[h];
    __syncthreads();   // G region dead -> Y bounce [16][8][68]

    #pragma unroll
    for (int tile = 0; tile < 2; ++tile) {
        const int im = tile ? iB : iA;
        #pragma unroll
        for (int mf = 0; mf < 2; ++mf) {
            const f32x16 ac = tile ? (mf ? acB1 : acB0) : (mf ? acA1 : acA0);
            #pragma unroll
            for (int rq = 0; rq < 4; ++rq) {
                const int row0 = mf * 32 + 8 * rq + 4 * q;
                uint2 uv2 = *(const uint2*)(smem + 17600 + im * 1152 + b * 144 + row0 * 2);
                unsigned short us[4] = { (unsigned short)(uv2.x & 0xffff),
                                         (unsigned short)(uv2.x >> 16),
                                         (unsigned short)(uv2.y & 0xffff),
                                         (unsigned short)(uv2.y >> 16) };
                unsigned short oh[4];
                #pragma unroll
                for (int k = 0; k < 4; ++k) {
                    float y = ac[rq * 4 + k] + Dh * bf2f(us[k]);
                    float g = 0.5f * y * (1.0f + erff(y * 0.70710678118654752f));
                    oh[k] = f2bf(g);
                }
                *(uint2*)(smem + im * 1088 + b * 136 + row0 * 2) = pack4(oh);
            }
        }
    }
    __syncthreads();
    {   // coalesced copy-out: Ybf[b][h][l]
        const int b2 = tid >> 4, e4 = (tid & 15) * 4;
        unsigned short* dst = YbfH + ((size_t)(b2 * 512 + h)) * 1024;
        #pragma unroll
        for (int j = 0; j < 16; ++j) {
            uint2 v = *(const uint2*)(smem + j * 1088 + b2 * 136 + e4 * 2);
            *(uint2*)&dst[j * 64 + e4] = v;
        }
    }
}

// transpose [b][c][l] -> [b][l][c] (hi plane only)
__global__ __launch_bounds__(256) void k_tr(const unsigned short* __restrict__ Ybf,
                                            unsigned short* __restrict__ Ytb) {
    __shared__ unsigned short tl[64][72];
    const int t = threadIdx.x;
    const int b = blockIdx.z;
    const int c0 = blockIdx.y * 64, l0 = blockIdx.x * 64;
    {
        const int c = t >> 2, lq = (t & 3) * 16;
        const unsigned short* src = Ybf + ((size_t)(b * 512 + c0 + c)) * 1024 + l0 + lq;
        uint4 v0 = *(const uint4*)src;
        uint4 v1 = *(const uint4*)(src + 8);
        *(uint4*)&tl[c][lq] = v0;
        *(uint4*)&tl[c][lq + 8] = v1;
    }
    __syncthreads();
    {
        const int l = t >> 2, cq = (t & 3) * 16;
        unsigned int o[8];
        #pragma unroll
        for (int k = 0; k < 8; ++k)
            o[k] = (unsigned)tl[cq + 2 * k][l] | ((unsigned)tl[cq + 2 * k + 1][l] << 16);
        unsigned short* dst = Ytb + ((size_t)(b * 1024 + l0 + l)) * 512 + c0 + cq;
        *(uint4*)dst = *(uint4*)&o[0];
        *(uint4*)(dst + 8) = *(uint4*)&o[4];
    }
}

// split-W bf16 MFMA GEMM (Wh*Yh + Wl*Yh) + bias/GLU/pool/dec epilogue
__global__ __launch_bounds__(256) void k2_gemm(const unsigned short* __restrict__ WbfH,
                                               const unsigned short* __restrict__ WbfL,
                                               const unsigned short* __restrict__ Ytb,
                                               const float* __restrict__ conv_b,
                                               const float* __restrict__ dec_w,
                                               float* __restrict__ partial) {
    __shared__ unsigned short WTh[128][40], WTl[128][40];
    __shared__ unsigned short YTh[128][40];
    __shared__ float red[4][64][20];
    const int tid = threadIdx.x, lane = tid & 63, wid = tid >> 6;
    const int b = blockIdx.z, oblk = blockIdx.y, lblk = blockIdx.x;
    const int o0 = oblk * 64, l0 = lblk * 128;
    const int fr = lane & 15, fq = lane >> 4;

    f32x4 acc[8][2] = {};

    const int srow = tid >> 1, skh = (tid & 1) * 16;
    const int grow = (srow < 64) ? (o0 + srow) : (512 + o0 + srow - 64);
    const size_t woff = (size_t)grow * 512 + skh;
    const size_t yoff = ((size_t)(b * 1024) + l0 + srow) * 512 + skh;

    for (int c0 = 0; c0 < 512; c0 += 32) {
        __syncthreads();
        uint4 wh0 = *(const uint4*)(WbfH + woff + c0);
        uint4 wh1 = *(const uint4*)(WbfH + woff + c0 + 8);
        uint4 wl0 = *(const uint4*)(WbfL + woff + c0);
        uint4 wl1 = *(const uint4*)(WbfL + woff + c0 + 8);
        uint4 yh0 = *(const uint4*)(Ytb + yoff + c0);
        uint4 yh1 = *(const uint4*)(Ytb + yoff + c0 + 8);
        *(uint4*)&WTh[srow][skh]     = wh0;
        *(uint4*)&WTh[srow][skh + 8] = wh1;
        *(uint4*)&WTl[srow][skh]     = wl0;
        *(uint4*)&WTl[srow][skh + 8] = wl1;
        *(uint4*)&YTh[srow][skh]     = yh0;
        *(uint4*)&YTh[srow][skh + 8] = yh1;
        __syncthreads();
        short8 b0h = *(const short8*)&YTh[wid * 32 + fr][fq * 8];
        short8 b1h = *(const short8*)&YTh[wid * 32 + 16 + fr][fq * 8];
        #pragma unroll
        for (int mf = 0; mf < 8; ++mf) {
            short8 ah = *(const short8*)&WTh[mf * 16 + fr][fq * 8];
            short8 al = *(const short8*)&WTl[mf * 16 + fr][fq * 8];
            acc[mf][0] = __builtin_amdgcn_mfma_f32_16x16x32_bf16(ah, b0h, acc[mf][0], 0, 0, 0);
            acc[mf][1] = __builtin_amdgcn_mfma_f32_16x16x32_bf16(ah, b1h, acc[mf][1], 0, 0, 0);
            acc[mf][0] = __builtin_amdgcn_mfma_f32_16x16x32_bf16(al, b0h, acc[mf][0], 0, 0, 0);
            acc[mf][1] = __builtin_amdgcn_mfma_f32_16x16x32_bf16(al, b1h, acc[mf][1], 0, 0, 0);
        }
    }

    #pragma unroll
    for (int mf = 0; mf < 4; ++mf)
        #pragma unroll
        for (int j = 0; j < 4; ++j) {
            int ol = mf * 16 + fq * 4 + j;
            float ba = conv_b[o0 + ol];
            float bb = conv_b[512 + o0 + ol];
            float s = 0.f;
            #pragma unroll
            for (int nf = 0; nf < 2; ++nf) {
                float za = acc[mf][nf][j] + ba;
                float zb = acc[mf + 4][nf][j] + bb;
                s += za / (1.f + expf(-zb));
            }
            red[wid][ol][fr] = s;
        }
    __syncthreads();
    if (tid < 64) {
        float s = 0.f;
        #pragma unroll
        for (int w = 0; w < 4; ++w) {
            float4 r0 = *(const float4*)&red[w][tid][0];
            float4 r1 = *(const float4*)&red[w][tid][4];
            float4 r2 = *(const float4*)&red[w][tid][8];
            float4 r3 = *(const float4*)&red[w][tid][12];
            s += (r0.x + r0.y + r0.z + r0.w) + (r1.x + r1.y + r1.z + r1.w)
               + (r2.x + r2.y + r2.z + r2.w) + (r3.x + r3.y + r3.z + r3.w);
        }
        float val = s * dec_w[o0 + tid] * (1.0f / 1024.0f);
        #pragma unroll
        for (int off = 32; off; off >>= 1) val += __shfl_xor(val, off);
        if (tid == 0) partial[((b * 8) + oblk) * 8 + lblk] = val;
    }
}

__global__ void k3_final(const float* __restrict__ partial,
                         const float* __restrict__ dec_b,
                         float* __restrict__ out) {
    int b = threadIdx.x;
    if (b < Bm) {
        float s = dec_b[0];
        for (int i = 0; i < 64; ++i) s += partial[b * 64 + i];
        out[b] = s;
    }
}

extern "C" void kernel_launch(void* const* d_in, const int* in_sizes, int n_in,
                              void* d_out, int out_size, void* d_ws, size_t ws_size,
                              hipStream_t stream) {
    const float* u          = (const float*)d_in[0];
    const float* log_dt     = (const float*)d_in[1];
    const float* log_A_real = (const float*)d_in[2];
    const float* A_imag     = (const float*)d_in[3];
    const float* B_real     = (const float*)d_in[4];
    const float* B_imag     = (const float*)d_in[5];
    const float* C_real     = (const float*)d_in[6];
    const float* C_imag     = (const float*)d_in[7];
    const float* Dvec       = (const float*)d_in[8];
    const float* conv_w     = (const float*)d_in[9];
    const float* conv_b     = (const float*)d_in[10];
    const float* dec_w      = (const float*)d_in[11];
    const float* dec_b      = (const float*)d_in[12];

    char* base = (char*)d_ws;
    float* par           = (float*)base;                                // 768 KB
    unsigned int* Krep   = (unsigned int*)(base + 1048576);             // 9.0 MB
    unsigned short* YbfH = (unsigned short*)(base + 10485760);          // 8 MB
    unsigned short* Ytb  = (unsigned short*)(base + 18874368);          // 8 MB
    unsigned short* Wh   = (unsigned short*)(base + 27262976);          // 1 MB
    unsigned short* Wl   = (unsigned short*)(base + 28311552);          // 1 MB
    float* partial       = (float*)(base + 29360128);                   // 2 KB
    float* out           = (float*)d_out;

    k0_params<<<128, 256, 0, stream>>>(log_dt, log_A_real, A_imag, B_real,
                                       B_imag, C_real, C_imag, par);
    k_cvt<<<512, 256, 0, stream>>>(conv_w, Wh, Wl);
    k_kgen<<<512, 256, 0, stream>>>(par, Krep);
    k_tconv<<<512, 128, 0, stream>>>(u, Dvec, Krep, YbfH);
    k_tr<<<dim3(16, 8, 8), 256, 0, stream>>>(YbfH, Ytb);
    k2_gemm<<<dim3(8, 8, 8), 256, 0, stream>>>(Wh, Wl, Ytb, conv_b, dec_w, partial);
    k3_final<<<1, 64, 0, stream>>>(partial, dec_b, out);
}

// Round 11
// 80.910 us; speedup vs baseline: 1.7019x; 1.0773x over previous
//
#include <hip/hip_runtime.h>
#include <hip/hip_bf16.h>
#include <math.h>

typedef __attribute__((ext_vector_type(8))) short short8;
typedef __attribute__((ext_vector_type(4))) float f32x4;
typedef __attribute__((ext_vector_type(16))) float f32x16;
typedef __attribute__((ext_vector_type(4))) unsigned int uint4v;

constexpr int Hm = 512, Lm = 1024, Bm = 8;

static __device__ __forceinline__ unsigned short f2bf(float f) {
    __hip_bfloat16 h = __float2bfloat16(f);
    return *reinterpret_cast<unsigned short*>(&h);
}
static __device__ __forceinline__ float bf2f(unsigned short u) {
    return __uint_as_float((unsigned)u << 16);
}
static __device__ __forceinline__ uint2 pack4(const unsigned short* x) {
    return make_uint2((unsigned)x[0] | ((unsigned)x[1] << 16),
                      (unsigned)x[2] | ((unsigned)x[3] << 16));
}
static __device__ __forceinline__ short8 ld16u(const char* p) {   // 2 x b64
    uint2 a = *(const uint2*)p;
    uint2 b = *(const uint2*)(p + 8);
    uint4v t = { a.x, a.y, b.x, b.y };
    return __builtin_bit_cast(short8, t);
}

// K generator with fused param math (ex-k0) and fused conv_w split (ex-k_cvt).
// Output: per h, packed dwords [plane(2)][rep(4)][550]: rep s dword d =
// bf16 (plane) of (G[2d+s], G[2d+1+s]); G[j]=K[j], 0 past 1023.
__global__ __launch_bounds__(256) void k_kgen(const float* __restrict__ log_dt,
                                              const float* __restrict__ log_A_real,
                                              const float* __restrict__ A_imag,
                                              const float* __restrict__ B_real,
                                              const float* __restrict__ B_imag,
                                              const float* __restrict__ C_real,
                                              const float* __restrict__ C_imag,
                                              const float* __restrict__ conv_w,
                                              unsigned int* __restrict__ Krep,
                                              unsigned short* __restrict__ Woh,
                                              unsigned short* __restrict__ Wol) {
    __shared__ __align__(16) char smem[22528];   // kl 4x4224 | Kf 4096 | pl 1536
    const int tid = threadIdx.x, lane = tid & 63, wid = tid >> 6;
    float* kl = (float*)smem + wid * 1056;       // [16][66] per wave
    float* Kf = (float*)(smem + 16896);          // [1024]
    float* pl = (float*)(smem + 20992);          // [6][64]
    const int h = blockIdx.x;

    // folded k_cvt: this block converts conv_w[h*1024 .. h*1024+1024)
    {
        int i = h * 1024 + tid * 4;
        float4 v = *(const float4*)&conv_w[i];
        unsigned short h0 = f2bf(v.x), h1 = f2bf(v.y), h2 = f2bf(v.z), h3 = f2bf(v.w);
        unsigned short l0 = f2bf(v.x - bf2f(h0));
        unsigned short l1 = f2bf(v.y - bf2f(h1));
        unsigned short l2 = f2bf(v.z - bf2f(h2));
        unsigned short l3 = f2bf(v.w - bf2f(h3));
        *(uint2*)&Woh[i] = make_uint2((unsigned)h0 | ((unsigned)h1 << 16),
                                      (unsigned)h2 | ((unsigned)h3 << 16));
        *(uint2*)&Wol[i] = make_uint2((unsigned)l0 | ((unsigned)l1 << 16),
                                      (unsigned)l2 | ((unsigned)l3 << 16));
    }
    // folded k0: per-state params (f64) into LDS
    if (tid < 64) {
        int idx = h * 64 + tid;
        double dt = exp((double)log_dt[h]);
        double Ar = -exp((double)log_A_real[idx]);
        double Ai = (double)A_imag[idx];
        double ar = Ar * dt, ai = Ai * dt;          // dtA
        double er = exp(ar);
        double rr = er * cos(ai), ri = er * sin(ai);        // r
        double nr = rr - 1.0, ni = ri;
        double den = Ar * Ar + Ai * Ai;
        double qr = (nr * Ar + ni * Ai) / den;
        double qi = (ni * Ar - nr * Ai) / den;
        double Br = (double)B_real[idx], Bi = (double)B_imag[idx];
        double bbr = qr * Br - qi * Bi, bbi = qr * Bi + qi * Br;
        double Cr = (double)C_real[idx], Ci = (double)C_imag[idx];
        double wr = Cr * bbr - Ci * bbi, wi = Cr * bbi + Ci * bbr;
        double e64 = exp(ar * 64.0);
        double p64 = ai * 64.0;
        pl[0 * 64 + tid] = (float)rr;
        pl[1 * 64 + tid] = (float)ri;
        pl[2 * 64 + tid] = (float)wr;
        pl[3 * 64 + tid] = (float)wi;
        pl[4 * 64 + tid] = (float)(e64 * cos(p64));
        pl[5 * 64 + tid] = (float)(e64 * sin(p64));
    }
    __syncthreads();

    const float rrf = pl[0 * 64 + lane], rif = pl[1 * 64 + lane];
    float pr = pl[2 * 64 + lane], pi = pl[3 * 64 + lane];   // w
    float br = pl[4 * 64 + lane], bi = pl[5 * 64 + lane];   // r^64
    int cc = wid * 4;
    while (cc) {   // p = w * (r^64)^(4*wid)
        if (cc & 1) { float t_ = pr * br - pi * bi; pi = fmaf(pr, bi, pi * br); pr = t_; }
        float t2 = br * br - bi * bi; bi = 2.f * br * bi; br = t2;
        cc >>= 1;
    }
    const int jj = lane & 15, nq = lane >> 4;
    for (int q = 0; q < 16; ++q) {
        #pragma unroll
        for (int j = 0; j < 16; ++j) {
            kl[j * 66 + lane] = pr;
            float t_ = pr * rrf - pi * rif; pi = fmaf(pr, rif, pi * rrf); pr = t_;
        }
        asm volatile("s_waitcnt lgkmcnt(0)" ::: "memory");
        float s0 = 0.f, s1 = 0.f;
        #pragma unroll
        for (int n = 0; n < 16; n += 4) {
            float2 a = *(const float2*)&kl[jj * 66 + nq * 16 + n];
            float2 b2 = *(const float2*)&kl[jj * 66 + nq * 16 + n + 2];
            s0 += a.x + a.y; s1 += b2.x + b2.y;
        }
        float s = s0 + s1;
        s += __shfl_xor(s, 16);
        s += __shfl_xor(s, 32);
        if (lane < 16) Kf[wid * 256 + q * 16 + jj] = s;
        asm volatile("s_waitcnt lgkmcnt(0)" ::: "memory");
    }
    __syncthreads();
    for (int t = tid; t < 4400; t += 256) {
        int p = t / 2200;
        int rem = t - p * 2200;
        int s = rem / 550;
        int d = rem - s * 550;
        int idx0 = 2 * d + s;
        float k0 = (idx0 < 1024) ? Kf[idx0] : 0.f;
        float k1 = (idx0 + 1 < 1024) ? Kf[idx0 + 1] : 0.f;
        unsigned short h0 = f2bf(k0), h1 = f2bf(k1);
        unsigned short v0, v1;
        if (p == 0) { v0 = h0; v1 = h1; }
        else { v0 = f2bf(k0 - bf2f(h0)); v1 = f2bf(k1 - bf2f(h1)); }
        Krep[(size_t)h * 4400 + t] = (unsigned)v0 | ((unsigned)v1 << 16);
    }
}

// Toeplitz block-conv, 32x32x16 MFMA, 2-tile blocking, software-pipelined:
// A-windows for d+1 prefetched after d's MFMAs issue (single buffer, WAR-safe).
// Geometry identical to the R10-proven version.
__global__ __launch_bounds__(128, 2) void k_tconv(const float* __restrict__ u,
                                                  const float* __restrict__ Dvec,
                                                  const unsigned int* __restrict__ Krep,
                                                  unsigned short* __restrict__ YbfH) {
    __shared__ __align__(16) char smem[36160];
    const int tid = threadIdx.x, lane = tid & 63, w = tid >> 6;
    const int h = blockIdx.x;
    const int m = lane & 31, q = lane >> 5;
    const int cg = (lane >> 3) & 3, b = lane & 7;

    {   // stage G (k_kgen layout == LDS layout)
        const uint4* src = (const uint4*)(Krep + (size_t)h * 4400);
        uint4* dst = (uint4*)smem;
        #pragma unroll
        for (int o = 0; o < 9; ++o) {
            int idx = tid + o * 128;
            if (idx < 1100) dst[idx] = src[idx];
        }
    }
    if (tid < 8) { uint4 z = {0, 0, 0, 0}; ((uint4*)(smem + 36032))[tid] = z; }
    {   // stage u -> [j][b][72] bf16
        const int b2 = tid >> 4, e4 = (tid & 15) * 4;
        const float* ub = u + ((size_t)(b2 * 512 + h)) * 1024;
        #pragma unroll
        for (int j = 0; j < 16; ++j) {
            float4 v = *(const float4*)&ub[j * 64 + e4];
            unsigned short t0 = f2bf(v.x), t1 = f2bf(v.y), t2 = f2bf(v.z), t3 = f2bf(v.w);
            *(uint2*)(smem + 17600 + j * 1152 + b2 * 144 + e4 * 2) =
                make_uint2((unsigned)t0 | ((unsigned)t1 << 16),
                           (unsigned)t2 | ((unsigned)t3 << 16));
        }
    }
    __syncthreads();

    const int iA = (cg & 2) ? ((cg & 1) ? 3 - w : 4 + w) : ((cg & 1) ? 7 - w : w);
    const int iB = iA + 8;
    const int tmaxA = 7 - w;
    const int dmax = 15 - w;

    const int ub0 = 17600 + b * 144 + q * 16;
    int aA = ub0 + iA * 1152;
    int aB = ub0 + iB * 1152;
    const int zl = 36032 + q * 16;

    const int r = (3 - m) & 3;
    int baseH = r * 2200 + (991 - m - r + 8 * q) * 2;
    int baseL = baseH + 8800;

    const f32x16 zacc = {};
    f32x16 acA0 = zacc, acA1 = zacc, acB0 = zacc, acB1 = zacc;

    // prologue: d=0 windows
    short8 m2h, m1h, w0h, w1h, w2h, w3h;
    short8 m2l, m1l, w0l, w1l, w2l, w3l;
    {
        const char* pH = smem + baseH;
        const char* pL = smem + baseL;
        m2h = ld16u(pH +   0); m1h = ld16u(pH +  32);
        w0h = ld16u(pH +  64); w1h = ld16u(pH +  96);
        w2h = ld16u(pH + 128); w3h = ld16u(pH + 160);
        m2l = ld16u(pL +   0); m1l = ld16u(pL +  32);
        w0l = ld16u(pL +  64); w1l = ld16u(pL +  96);
        w2l = ld16u(pL + 128); w3l = ld16u(pL + 160);
    }

    for (int d = 0; d <= dmax; ++d) {
        // B loads first (latency overlaps tileA work)
        const char* pbB = smem + ((d <= iB) ? aB : zl);
        short8 bB0 = *(const short8*)(pbB +  0);
        short8 bB1 = *(const short8*)(pbB + 32);
        short8 bB2 = *(const short8*)(pbB + 64);
        short8 bB3 = *(const short8*)(pbB + 96);

        if (d <= tmaxA) {   // tile A
            const char* pbA = smem + ((d <= iA) ? aA : zl);
            short8 bA0 = *(const short8*)(pbA +  0);
            short8 bA1 = *(const short8*)(pbA + 32);
            short8 bA2 = *(const short8*)(pbA + 64);
            short8 bA3 = *(const short8*)(pbA + 96);
            acA0 = __builtin_amdgcn_mfma_f32_32x32x16_bf16(w0h, bA0, acA0, 0, 0, 0);
            acA0 = __builtin_amdgcn_mfma_f32_32x32x16_bf16(w0l, bA0, acA0, 0, 0, 0);
            acA1 = __builtin_amdgcn_mfma_f32_32x32x16_bf16(m2h, bA0, acA1, 0, 0, 0);
            acA1 = __builtin_amdgcn_mfma_f32_32x32x16_bf16(m2l, bA0, acA1, 0, 0, 0);
            acA0 = __builtin_amdgcn_mfma_f32_32x32x16_bf16(w1h, bA1, acA0, 0, 0, 0);
            acA0 = __builtin_amdgcn_mfma_f32_32x32x16_bf16(w1l, bA1, acA0, 0, 0, 0);
            acA1 = __builtin_amdgcn_mfma_f32_32x32x16_bf16(m1h, bA1, acA1, 0, 0, 0);
            acA1 = __builtin_amdgcn_mfma_f32_32x32x16_bf16(m1l, bA1, acA1, 0, 0, 0);
            acA0 = __builtin_amdgcn_mfma_f32_32x32x16_bf16(w2h, bA2, acA0, 0, 0, 0);
            acA0 = __builtin_amdgcn_mfma_f32_32x32x16_bf16(w2l, bA2, acA0, 0, 0, 0);
            acA1 = __builtin_amdgcn_mfma_f32_32x32x16_bf16(w0h, bA2, acA1, 0, 0, 0);
            acA1 = __builtin_amdgcn_mfma_f32_32x32x16_bf16(w0l, bA2, acA1, 0, 0, 0);
            acA0 = __builtin_amdgcn_mfma_f32_32x32x16_bf16(w3h, bA3, acA0, 0, 0, 0);
            acA0 = __builtin_amdgcn_mfma_f32_32x32x16_bf16(w3l, bA3, acA0, 0, 0, 0);
            acA1 = __builtin_amdgcn_mfma_f32_32x32x16_bf16(w1h, bA3, acA1, 0, 0, 0);
            acA1 = __builtin_amdgcn_mfma_f32_32x32x16_bf16(w1l, bA3, acA1, 0, 0, 0);
        }
        {   // tile B
            acB0 = __builtin_amdgcn_mfma_f32_32x32x16_bf16(w0h, bB0, acB0, 0, 0, 0);
            acB0 = __builtin_amdgcn_mfma_f32_32x32x16_bf16(w0l, bB0, acB0, 0, 0, 0);
            acB1 = __builtin_amdgcn_mfma_f32_32x32x16_bf16(m2h, bB0, acB1, 0, 0, 0);
            acB1 = __builtin_amdgcn_mfma_f32_32x32x16_bf16(m2l, bB0, acB1, 0, 0, 0);
            acB0 = __builtin_amdgcn_mfma_f32_32x32x16_bf16(w1h, bB1, acB0, 0, 0, 0);
            acB0 = __builtin_amdgcn_mfma_f32_32x32x16_bf16(w1l, bB1, acB0, 0, 0, 0);
            acB1 = __builtin_amdgcn_mfma_f32_32x32x16_bf16(m1h, bB1, acB1, 0, 0, 0);
            acB1 = __builtin_amdgcn_mfma_f32_32x32x16_bf16(m1l, bB1, acB1, 0, 0, 0);
            acB0 = __builtin_amdgcn_mfma_f32_32x32x16_bf16(w2h, bB2, acB0, 0, 0, 0);
            acB0 = __builtin_amdgcn_mfma_f32_32x32x16_bf16(w2l, bB2, acB0, 0, 0, 0);
            acB1 = __builtin_amdgcn_mfma_f32_32x32x16_bf16(w0h, bB2, acB1, 0, 0, 0);
            acB1 = __builtin_amdgcn_mfma_f32_32x32x16_bf16(w0l, bB2, acB1, 0, 0, 0);
            acB0 = __builtin_amdgcn_mfma_f32_32x32x16_bf16(w3h, bB3, acB0, 0, 0, 0);
            acB0 = __builtin_amdgcn_mfma_f32_32x32x16_bf16(w3l, bB3, acB0, 0, 0, 0);
            acB1 = __builtin_amdgcn_mfma_f32_32x32x16_bf16(w1h, bB3, acB1, 0, 0, 0);
            acB1 = __builtin_amdgcn_mfma_f32_32x32x16_bf16(w1l, bB3, acB1, 0, 0, 0);
        }
        baseH -= 128; baseL -= 128; aA -= 1152; aB -= 1152;
        if (d < dmax) {   // prefetch d+1 windows (MFMAs above already issued)
            const char* pH = smem + baseH;
            const char* pL = smem + baseL;
            m2h = ld16u(pH +   0); m1h = ld16u(pH +  32);
            w0h = ld16u(pH +  64); w1h = ld16u(pH +  96);
            w2h = ld16u(pH + 128); w3h = ld16u(pH + 160);
            m2l = ld16u(pL +   0); m1l = ld16u(pL +  32);
            w0l = ld16u(pL +  64); w1l = ld16u(pL +  96);
            w2l = ld16u(pL + 128); w3l = ld16u(pL + 160);
        }
    }

    const float Dh = Dvec[h];
    __syncthreads();   // G region dead -> Y bounce [16][8][68]

    #pragma unroll
    for (int tile = 0; tile < 2; ++tile) {
        const int im = tile ? iB : iA;
        #pragma unroll
        for (int mf = 0; mf < 2; ++mf) {
            const f32x16 ac = tile ? (mf ? acB1 : acB0) : (mf ? acA1 : acA0);
            #pragma unroll
            for (int rq = 0; rq < 4; ++rq) {
                const int row0 = mf * 32 + 8 * rq + 4 * q;
                uint2 uv2 = *(const uint2*)(smem + 17600 + im * 1152 + b * 144 + row0 * 2);
                unsigned short us[4] = { (unsigned short)(uv2.x & 0xffff),
                                         (unsigned short)(uv2.x >> 16),
                                         (unsigned short)(uv2.y & 0xffff),
                                         (unsigned short)(uv2.y >> 16) };
                unsigned short oh[4];
                #pragma unroll
                for (int k = 0; k < 4; ++k) {
                    float y = ac[rq * 4 + k] + Dh * bf2f(us[k]);
                    float g = 0.5f * y * (1.0f + erff(y * 0.70710678118654752f));
                    oh[k] = f2bf(g);
                }
                *(uint2*)(smem + im * 1088 + b * 136 + row0 * 2) = pack4(oh);
            }
        }
    }
    __syncthreads();
    {   // coalesced copy-out: Ybf[b][h][l]
        const int b2 = tid >> 4, e4 = (tid & 15) * 4;
        unsigned short* dst = YbfH + ((size_t)(b2 * 512 + h)) * 1024;
        #pragma unroll
        for (int j = 0; j < 16; ++j) {
            uint2 v = *(const uint2*)(smem + j * 1088 + b2 * 136 + e4 * 2);
            *(uint2*)&dst[j * 64 + e4] = v;
        }
    }
}

// transpose [b][c][l] -> [b][l][c] (hi plane only)
__global__ __launch_bounds__(256) void k_tr(const unsigned short* __restrict__ Ybf,
                                            unsigned short* __restrict__ Ytb) {
    __shared__ unsigned short tl[64][72];
    const int t = threadIdx.x;
    const int b = blockIdx.z;
    const int c0 = blockIdx.y * 64, l0 = blockIdx.x * 64;
    {
        const int c = t >> 2, lq = (t & 3) * 16;
        const unsigned short* src = Ybf + ((size_t)(b * 512 + c0 + c)) * 1024 + l0 + lq;
        uint4 v0 = *(const uint4*)src;
        uint4 v1 = *(const uint4*)(src + 8);
        *(uint4*)&tl[c][lq] = v0;
        *(uint4*)&tl[c][lq + 8] = v1;
    }
    __syncthreads();
    {
        const int l = t >> 2, cq = (t & 3) * 16;
        unsigned int o[8];
        #pragma unroll
        for (int k = 0; k < 8; ++k)
            o[k] = (unsigned)tl[cq + 2 * k][l] | ((unsigned)tl[cq + 2 * k + 1][l] << 16);
        unsigned short* dst = Ytb + ((size_t)(b * 1024 + l0 + l)) * 512 + c0 + cq;
        *(uint4*)dst = *(uint4*)&o[0];
        *(uint4*)(dst + 8) = *(uint4*)&o[4];
    }
}

// split-W bf16 MFMA GEMM (Wh*Yh + Wl*Yh) + bias/GLU/pool/dec epilogue
__global__ __launch_bounds__(256) void k2_gemm(const unsigned short* __restrict__ WbfH,
                                               const unsigned short* __restrict__ WbfL,
                                               const unsigned short* __restrict__ Ytb,
                                               const float* __restrict__ conv_b,
                                               const float* __restrict__ dec_w,
                                               float* __restrict__ partial) {
    __shared__ unsigned short WTh[128][40], WTl[128][40];
    __shared__ unsigned short YTh[128][40];
    __shared__ float red[4][64][20];
    const int tid = threadIdx.x, lane = tid & 63, wid = tid >> 6;
    const int b = blockIdx.z, oblk = blockIdx.y, lblk = blockIdx.x;
    const int o0 = oblk * 64, l0 = lblk * 128;
    const int fr = lane & 15, fq = lane >> 4;

    f32x4 acc[8][2] = {};

    const int srow = tid >> 1, skh = (tid & 1) * 16;
    const int grow = (srow < 64) ? (o0 + srow) : (512 + o0 + srow - 64);
    const size_t woff = (size_t)grow * 512 + skh;
    const size_t yoff = ((size_t)(b * 1024) + l0 + srow) * 512 + skh;

    for (int c0 = 0; c0 < 512; c0 += 32) {
        __syncthreads();
        uint4 wh0 = *(const uint4*)(WbfH + woff + c0);
        uint4 wh1 = *(const uint4*)(WbfH + woff + c0 + 8);
        uint4 wl0 = *(const uint4*)(WbfL + woff + c0);
        uint4 wl1 = *(const uint4*)(WbfL + woff + c0 + 8);
        uint4 yh0 = *(const uint4*)(Ytb + yoff + c0);
        uint4 yh1 = *(const uint4*)(Ytb + yoff + c0 + 8);
        *(uint4*)&WTh[srow][skh]     = wh0;
        *(uint4*)&WTh[srow][skh + 8] = wh1;
        *(uint4*)&WTl[srow][skh]     = wl0;
        *(uint4*)&WTl[srow][skh + 8] = wl1;
        *(uint4*)&YTh[srow][skh]     = yh0;
        *(uint4*)&YTh[srow][skh + 8] = yh1;
        __syncthreads();
        short8 b0h = *(const short8*)&YTh[wid * 32 + fr][fq * 8];
        short8 b1h = *(const short8*)&YTh[wid * 32 + 16 + fr][fq * 8];
        #pragma unroll
        for (int mf = 0; mf < 8; ++mf) {
            short8 ah = *(const short8*)&WTh[mf * 16 + fr][fq * 8];
            short8 al = *(const short8*)&WTl[mf * 16 + fr][fq * 8];
            acc[mf][0] = __builtin_amdgcn_mfma_f32_16x16x32_bf16(ah, b0h, acc[mf][0], 0, 0, 0);
            acc[mf][1] = __builtin_amdgcn_mfma_f32_16x16x32_bf16(ah, b1h, acc[mf][1], 0, 0, 0);
            acc[mf][0] = __builtin_amdgcn_mfma_f32_16x16x32_bf16(al, b0h, acc[mf][0], 0, 0, 0);
            acc[mf][1] = __builtin_amdgcn_mfma_f32_16x16x32_bf16(al, b1h, acc[mf][1], 0, 0, 0);
        }
    }

    #pragma unroll
    for (int mf = 0; mf < 4; ++mf)
        #pragma unroll
        for (int j = 0; j < 4; ++j) {
            int ol = mf * 16 + fq * 4 + j;
            float ba = conv_b[o0 + ol];
            float bb = conv_b[512 + o0 + ol];
            float s = 0.f;
            #pragma unroll
            for (int nf = 0; nf < 2; ++nf) {
                float za = acc[mf][nf][j] + ba;
                float zb = acc[mf + 4][nf][j] + bb;
                s += za / (1.f + expf(-zb));
            }
            red[wid][ol][fr] = s;
        }
    __syncthreads();
    if (tid < 64) {
        float s = 0.f;
        #pragma unroll
        for (int w = 0; w < 4; ++w) {
            float4 r0 = *(const float4*)&red[w][tid][0];
            float4 r1 = *(const float4*)&red[w][tid][4];
            float4 r2 = *(const float4*)&red[w][tid][8];
            float4 r3 = *(const float4*)&red[w][tid][12];
            s += (r0.x + r0.y + r0.z + r0.w) + (r1.x + r1.y + r1.z + r1.w)
               + (r2.x + r2.y + r2.z + r2.w) + (r3.x + r3.y + r3.z + r3.w);
        }
        float val = s * dec_w[o0 + tid] * (1.0f / 1024.0f);
        #pragma unroll
        for (int off = 32; off; off >>= 1) val += __shfl_xor(val, off);
        if (tid == 0) partial[((b * 8) + oblk) * 8 + lblk] = val;
    }
}

__global__ void k3_final(const float* __restrict__ partial,
                         const float* __restrict__ dec_b,
                         float* __restrict__ out) {
    int b = threadIdx.x;
    if (b < Bm) {
        float s = dec_b[0];
        for (int i = 0; i < 64; ++i) s += partial[b * 64 + i];
        out[b] = s;
    }
}

extern "C" void kernel_launch(void* const* d_in, const int* in_sizes, int n_in,
                              void* d_out, int out_size, void* d_ws, size_t ws_size,
                              hipStream_t stream) {
    const float* u          = (const float*)d_in[0];
    const float* log_dt     = (const float*)d_in[1];
    const float* log_A_real = (const float*)d_in[2];
    const float* A_imag     = (const float*)d_in[3];
    const float* B_real     = (const float*)d_in[4];
    const float* B_imag     = (const float*)d_in[5];
    const float* C_real     = (const float*)d_in[6];
    const float* C_imag     = (const float*)d_in[7];
    const float* Dvec       = (const float*)d_in[8];
    const float* conv_w     = (const float*)d_in[9];
    const float* conv_b     = (const float*)d_in[10];
    const float* dec_w      = (const float*)d_in[11];
    const float* dec_b      = (const float*)d_in[12];

    char* base = (char*)d_ws;
    unsigned int* Krep   = (unsigned int*)base;                         // 9.0 MB
    unsigned short* YbfH = (unsigned short*)(base + 9437184);           // 8 MB
    unsigned short* Ytb  = (unsigned short*)(base + 17825792);          // 8 MB
    unsigned short* Wh   = (unsigned short*)(base + 26214400);          // 1 MB
    unsigned short* Wl   = (unsigned short*)(base + 27262976);          // 1 MB
    float* partial       = (float*)(base + 28311552);                   // 2 KB
    float* out           = (float*)d_out;

    k_kgen<<<512, 256, 0, stream>>>(log_dt, log_A_real, A_imag, B_real, B_imag,
                                    C_real, C_imag, conv_w, Krep, Wh, Wl);
    k_tconv<<<512, 128, 0, stream>>>(u, Dvec, Krep, YbfH);
    k_tr<<<dim3(16, 8, 8), 256, 0, stream>>>(YbfH, Ytb);
    k2_gemm<<<dim3(8, 8, 8), 256, 0, stream>>>(Wh, Wl, Ytb, conv_b, dec_w, partial);
    k3_final<<<1, 64, 0, stream>>>(partial, dec_b, out);
}

// Round 12
// 67.665 us; speedup vs baseline: 2.0351x; 1.1958x over previous
//
#include <hip/hip_runtime.h>
#include <hip/hip_bf16.h>
#include <math.h>

typedef __attribute__((ext_vector_type(8))) short short8;
typedef __attribute__((ext_vector_type(4))) float f32x4;
typedef __attribute__((ext_vector_type(16))) float f32x16;
typedef __attribute__((ext_vector_type(4))) unsigned int uint4v;

constexpr int Hm = 512, Lm = 1024, Bm = 8;

static __device__ __forceinline__ unsigned short f2bf(float f) {
    __hip_bfloat16 h = __float2bfloat16(f);
    return *reinterpret_cast<unsigned short*>(&h);
}
static __device__ __forceinline__ float bf2f(unsigned short u) {
    return __uint_as_float((unsigned)u << 16);
}
static __device__ __forceinline__ uint2 pack4(const unsigned short* x) {
    return make_uint2((unsigned)x[0] | ((unsigned)x[1] << 16),
                      (unsigned)x[2] | ((unsigned)x[3] << 16));
}
static __device__ __forceinline__ short8 ld16u(const char* p) {   // 2 x b64
    uint2 a = *(const uint2*)p;
    uint2 b = *(const uint2*)(p + 8);
    uint4v t = { a.x, a.y, b.x, b.y };
    return __builtin_bit_cast(short8, t);
}

// K generator + fused param math + fused conv_w hi/lo split.
// Krep per h: 2200 dwords [rep(4)][550]: rep s dword d = bf16-hi of
// (G[2d+s], G[2d+1+s]); G[j]=K[j], zeros past 1023.
__global__ __launch_bounds__(256) void k_kgen(const float* __restrict__ log_dt,
                                              const float* __restrict__ log_A_real,
                                              const float* __restrict__ A_imag,
                                              const float* __restrict__ B_real,
                                              const float* __restrict__ B_imag,
                                              const float* __restrict__ C_real,
                                              const float* __restrict__ C_imag,
                                              const float* __restrict__ conv_w,
                                              unsigned int* __restrict__ Krep,
                                              unsigned short* __restrict__ Woh,
                                              unsigned short* __restrict__ Wol) {
    __shared__ __align__(16) char smem[22528];   // kl 4x4224 | Kf 4096 | pl 1536
    const int tid = threadIdx.x, lane = tid & 63, wid = tid >> 6;
    float* kl = (float*)smem + wid * 1056;       // [16][66] per wave
    float* Kf = (float*)(smem + 16896);          // [1024]
    float* pl = (float*)(smem + 20992);          // [6][64]
    const int h = blockIdx.x;

    {   // folded conv_w split: this block converts rows h*2 (1024 floats)
        int i = h * 1024 + tid * 4;
        float4 v = *(const float4*)&conv_w[i];
        unsigned short h0 = f2bf(v.x), h1 = f2bf(v.y), h2 = f2bf(v.z), h3 = f2bf(v.w);
        unsigned short l0 = f2bf(v.x - bf2f(h0));
        unsigned short l1 = f2bf(v.y - bf2f(h1));
        unsigned short l2 = f2bf(v.z - bf2f(h2));
        unsigned short l3 = f2bf(v.w - bf2f(h3));
        *(uint2*)&Woh[i] = make_uint2((unsigned)h0 | ((unsigned)h1 << 16),
                                      (unsigned)h2 | ((unsigned)h3 << 16));
        *(uint2*)&Wol[i] = make_uint2((unsigned)l0 | ((unsigned)l1 << 16),
                                      (unsigned)l2 | ((unsigned)l3 << 16));
    }
    if (tid < 64) {   // folded param math (f64)
        int idx = h * 64 + tid;
        double dt = exp((double)log_dt[h]);
        double Ar = -exp((double)log_A_real[idx]);
        double Ai = (double)A_imag[idx];
        double ar = Ar * dt, ai = Ai * dt;
        double er = exp(ar);
        double rr = er * cos(ai), ri = er * sin(ai);
        double nr = rr - 1.0, ni = ri;
        double den = Ar * Ar + Ai * Ai;
        double qr = (nr * Ar + ni * Ai) / den;
        double qi = (ni * Ar - nr * Ai) / den;
        double Br = (double)B_real[idx], Bi = (double)B_imag[idx];
        double bbr = qr * Br - qi * Bi, bbi = qr * Bi + qi * Br;
        double Cr = (double)C_real[idx], Ci = (double)C_imag[idx];
        double wr = Cr * bbr - Ci * bbi, wi = Cr * bbi + Ci * bbr;
        double e64 = exp(ar * 64.0);
        double p64 = ai * 64.0;
        pl[0 * 64 + tid] = (float)rr;
        pl[1 * 64 + tid] = (float)ri;
        pl[2 * 64 + tid] = (float)wr;
        pl[3 * 64 + tid] = (float)wi;
        pl[4 * 64 + tid] = (float)(e64 * cos(p64));
        pl[5 * 64 + tid] = (float)(e64 * sin(p64));
    }
    __syncthreads();

    const float rrf = pl[0 * 64 + lane], rif = pl[1 * 64 + lane];
    float pr = pl[2 * 64 + lane], pi = pl[3 * 64 + lane];   // w
    float br = pl[4 * 64 + lane], bi = pl[5 * 64 + lane];   // r^64
    int cc = wid * 4;
    while (cc) {   // p = w * (r^64)^(4*wid)
        if (cc & 1) { float t_ = pr * br - pi * bi; pi = fmaf(pr, bi, pi * br); pr = t_; }
        float t2 = br * br - bi * bi; bi = 2.f * br * bi; br = t2;
        cc >>= 1;
    }
    const int jj = lane & 15, nq = lane >> 4;
    for (int q = 0; q < 16; ++q) {
        #pragma unroll
        for (int j = 0; j < 16; ++j) {
            kl[j * 66 + lane] = pr;
            float t_ = pr * rrf - pi * rif; pi = fmaf(pr, rif, pi * rrf); pr = t_;
        }
        asm volatile("s_waitcnt lgkmcnt(0)" ::: "memory");
        float s0 = 0.f, s1 = 0.f;
        #pragma unroll
        for (int n = 0; n < 16; n += 4) {
            float2 a = *(const float2*)&kl[jj * 66 + nq * 16 + n];
            float2 b2 = *(const float2*)&kl[jj * 66 + nq * 16 + n + 2];
            s0 += a.x + a.y; s1 += b2.x + b2.y;
        }
        float s = s0 + s1;
        s += __shfl_xor(s, 16);
        s += __shfl_xor(s, 32);
        if (lane < 16) Kf[wid * 256 + q * 16 + jj] = s;
        asm volatile("s_waitcnt lgkmcnt(0)" ::: "memory");
    }
    __syncthreads();
    for (int t = tid; t < 2200; t += 256) {
        int s = t / 550;
        int d = t - s * 550;
        int idx0 = 2 * d + s;
        float k0 = (idx0 < 1024) ? Kf[idx0] : 0.f;
        float k1 = (idx0 + 1 < 1024) ? Kf[idx0 + 1] : 0.f;
        Krep[(size_t)h * 2200 + t] = (unsigned)f2bf(k0) | ((unsigned)f2bf(k1) << 16);
    }
}

// Toeplitz block-conv, 32x32x16 MFMA, K-hi only, 4 waves x 1 tile.
// One block per h (256 thr). Wave w owns chunks {w, 7-w, 8+w, 15-w} = one
// N=32 tile (4 chunks x 8 batches). A[m][k] = G[1023-64d-32mf-m+16ks+8q+j].
// LDS: G hi [0,8800) = [rep4][1100]; u [17600,36032) = [16jc][8b][72us];
// zeros [36032,36160). Y bounce reuses [0,17408) after d-loop.
__global__ __launch_bounds__(256, 2) void k_tconv(const float* __restrict__ u,
                                                  const float* __restrict__ Dvec,
                                                  const unsigned int* __restrict__ Krep,
                                                  unsigned short* __restrict__ YbfH) {
    __shared__ __align__(16) char smem[36160];
    const int tid = threadIdx.x, lane = tid & 63, w = tid >> 6;   // 4 waves
    const int h = blockIdx.x;
    const int m = lane & 31, q = lane >> 5;
    const int cg = (lane >> 3) & 3, b = lane & 7;

    {   // stage G hi replicas (550 uint4)
        const uint4* src = (const uint4*)(Krep + (size_t)h * 2200);
        uint4* dst = (uint4*)smem;
        for (int o = tid; o < 550; o += 256) dst[o] = src[o];
    }
    if (tid < 8) { uint4 z = {0, 0, 0, 0}; ((uint4*)(smem + 36032))[tid] = z; }
    {   // stage u -> [jc][b][72] bf16
        const int b2 = tid >> 5, t32 = tid & 31;
        const float* ub = u + ((size_t)(b2 * 512 + h)) * 1024;
        #pragma unroll
        for (int g = 0; g < 8; ++g) {
            int s = t32 * 4 + g * 128;
            float4 v = *(const float4*)&ub[s];
            unsigned short t0 = f2bf(v.x), t1 = f2bf(v.y), t2 = f2bf(v.z), t3 = f2bf(v.w);
            int jc = s >> 6, e = s & 63;
            *(uint2*)(smem + 17600 + jc * 1152 + b2 * 144 + e * 2) =
                make_uint2((unsigned)t0 | ((unsigned)t1 << 16),
                           (unsigned)t2 | ((unsigned)t3 << 16));
        }
    }
    __syncthreads();

    // per-lane chunk within this wave's tile
    const int icg = (cg == 0) ? w : (cg == 1) ? 7 - w : (cg == 2) ? 8 + w : 15 - w;
    const int dmax = 15 - w;

    int aU = 17600 + icg * 1152 + b * 144 + q * 16;
    const int zl = 36032 + q * 16;

    const int r = (3 - m) & 3;
    int baseH = r * 2200 + (991 - m - r + 8 * q) * 2;

    const f32x16 zacc = {};
    f32x16 acc0 = zacc, acc1 = zacc;

    // prologue: d=0 windows (E-offsets -32,-16,0,16,32,48)
    short8 m2, m1, w0, w1, w2, w3;
    {
        const char* pH = smem + baseH;
        m2 = ld16u(pH +   0); m1 = ld16u(pH +  32);
        w0 = ld16u(pH +  64); w1 = ld16u(pH +  96);
        w2 = ld16u(pH + 128); w3 = ld16u(pH + 160);
    }

    for (int d = 0; d <= dmax; ++d) {
        const char* pb = smem + ((d <= icg) ? aU : zl);
        short8 b0 = *(const short8*)(pb +  0);
        short8 b1 = *(const short8*)(pb + 32);
        short8 b2 = *(const short8*)(pb + 64);
        short8 b3 = *(const short8*)(pb + 96);
        acc0 = __builtin_amdgcn_mfma_f32_32x32x16_bf16(w0, b0, acc0, 0, 0, 0);
        acc1 = __builtin_amdgcn_mfma_f32_32x32x16_bf16(m2, b0, acc1, 0, 0, 0);
        acc0 = __builtin_amdgcn_mfma_f32_32x32x16_bf16(w1, b1, acc0, 0, 0, 0);
        acc1 = __builtin_amdgcn_mfma_f32_32x32x16_bf16(m1, b1, acc1, 0, 0, 0);
        acc0 = __builtin_amdgcn_mfma_f32_32x32x16_bf16(w2, b2, acc0, 0, 0, 0);
        acc1 = __builtin_amdgcn_mfma_f32_32x32x16_bf16(w0, b2, acc1, 0, 0, 0);
        acc0 = __builtin_amdgcn_mfma_f32_32x32x16_bf16(w3, b3, acc0, 0, 0, 0);
        acc1 = __builtin_amdgcn_mfma_f32_32x32x16_bf16(w1, b3, acc1, 0, 0, 0);
        baseH -= 128; aU -= 1152;
        if (d < dmax) {   // prefetch d+1 windows
            const char* pH = smem + baseH;
            m2 = ld16u(pH +   0); m1 = ld16u(pH +  32);
            w0 = ld16u(pH +  64); w1 = ld16u(pH +  96);
            w2 = ld16u(pH + 128); w3 = ld16u(pH + 160);
        }
    }

    const float Dh = Dvec[h];
    __syncthreads();   // G region dead -> Y bounce [16][8][68]

    #pragma unroll
    for (int mf = 0; mf < 2; ++mf) {
        const f32x16 ac = mf ? acc1 : acc0;
        #pragma unroll
        for (int rq = 0; rq < 4; ++rq) {
            const int row0 = mf * 32 + 8 * rq + 4 * q;
            uint2 uv2 = *(const uint2*)(smem + 17600 + icg * 1152 + b * 144 + row0 * 2);
            unsigned short us[4] = { (unsigned short)(uv2.x & 0xffff),
                                     (unsigned short)(uv2.x >> 16),
                                     (unsigned short)(uv2.y & 0xffff),
                                     (unsigned short)(uv2.y >> 16) };
            unsigned short oh[4];
            #pragma unroll
            for (int k = 0; k < 4; ++k) {
                float y = ac[rq * 4 + k] + Dh * bf2f(us[k]);
                float g = 0.5f * y * (1.0f + erff(y * 0.70710678118654752f));
                oh[k] = f2bf(g);
            }
            *(uint2*)(smem + icg * 1088 + b * 136 + row0 * 2) = pack4(oh);
        }
    }
    __syncthreads();
    {   // coalesced copy-out: Ybf[b][h][l]
        const int b2 = tid >> 5, t32 = tid & 31;
        unsigned short* dst = YbfH + ((size_t)(b2 * 512 + h)) * 1024;
        #pragma unroll
        for (int g = 0; g < 8; ++g) {
            int s = t32 * 4 + g * 128;
            int jc = s >> 6, e = s & 63;
            uint2 v = *(const uint2*)(smem + jc * 1088 + b2 * 136 + e * 2);
            *(uint2*)&dst[s] = v;
        }
    }
}

// transpose [b][c][l] -> [b][l][c] (hi plane only)
__global__ __launch_bounds__(256) void k_tr(const unsigned short* __restrict__ Ybf,
                                            unsigned short* __restrict__ Ytb) {
    __shared__ unsigned short tl[64][72];
    const int t = threadIdx.x;
    const int b = blockIdx.z;
    const int c0 = blockIdx.y * 64, l0 = blockIdx.x * 64;
    {
        const int c = t >> 2, lq = (t & 3) * 16;
        const unsigned short* src = Ybf + ((size_t)(b * 512 + c0 + c)) * 1024 + l0 + lq;
        uint4 v0 = *(const uint4*)src;
        uint4 v1 = *(const uint4*)(src + 8);
        *(uint4*)&tl[c][lq] = v0;
        *(uint4*)&tl[c][lq + 8] = v1;
    }
    __syncthreads();
    {
        const int l = t >> 2, cq = (t & 3) * 16;
        unsigned int o[8];
        #pragma unroll
        for (int k = 0; k < 8; ++k)
            o[k] = (unsigned)tl[cq + 2 * k][l] | ((unsigned)tl[cq + 2 * k + 1][l] << 16);
        unsigned short* dst = Ytb + ((size_t)(b * 1024 + l0 + l)) * 512 + c0 + cq;
        *(uint4*)dst = *(uint4*)&o[0];
        *(uint4*)(dst + 8) = *(uint4*)&o[4];
    }
}

// split-W bf16 MFMA GEMM (Wh*Yh + Wl*Yh) + bias/GLU/pool/dec epilogue
__global__ __launch_bounds__(256) void k2_gemm(const unsigned short* __restrict__ WbfH,
                                               const unsigned short* __restrict__ WbfL,
                                               const unsigned short* __restrict__ Ytb,
                                               const float* __restrict__ conv_b,
                                               const float* __restrict__ dec_w,
                                               float* __restrict__ partial) {
    __shared__ unsigned short WTh[128][40], WTl[128][40];
    __shared__ unsigned short YTh[128][40];
    __shared__ float red[4][64][20];
    const int tid = threadIdx.x, lane = tid & 63, wid = tid >> 6;
    const int b = blockIdx.z, oblk = blockIdx.y, lblk = blockIdx.x;
    const int o0 = oblk * 64, l0 = lblk * 128;
    const int fr = lane & 15, fq = lane >> 4;

    f32x4 acc[8][2] = {};

    const int srow = tid >> 1, skh = (tid & 1) * 16;
    const int grow = (srow < 64) ? (o0 + srow) : (512 + o0 + srow - 64);
    const size_t woff = (size_t)grow * 512 + skh;
    const size_t yoff = ((size_t)(b * 1024) + l0 + srow) * 512 + skh;

    for (int c0 = 0; c0 < 512; c0 += 32) {
        __syncthreads();
        uint4 wh0 = *(const uint4*)(WbfH + woff + c0);
        uint4 wh1 = *(const uint4*)(WbfH + woff + c0 + 8);
        uint4 wl0 = *(const uint4*)(WbfL + woff + c0);
        uint4 wl1 = *(const uint4*)(WbfL + woff + c0 + 8);
        uint4 yh0 = *(const uint4*)(Ytb + yoff + c0);
        uint4 yh1 = *(const uint4*)(Ytb + yoff + c0 + 8);
        *(uint4*)&WTh[srow][skh]     = wh0;
        *(uint4*)&WTh[srow][skh + 8] = wh1;
        *(uint4*)&WTl[srow][skh]     = wl0;
        *(uint4*)&WTl[srow][skh + 8] = wl1;
        *(uint4*)&YTh[srow][skh]     = yh0;
        *(uint4*)&YTh[srow][skh + 8] = yh1;
        __syncthreads();
        short8 b0h = *(const short8*)&YTh[wid * 32 + fr][fq * 8];
        short8 b1h = *(const short8*)&YTh[wid * 32 + 16 + fr][fq * 8];
        #pragma unroll
        for (int mf = 0; mf < 8; ++mf) {
            short8 ah = *(const short8*)&WTh[mf * 16 + fr][fq * 8];
            short8 al = *(const short8*)&WTl[mf * 16 + fr][fq * 8];
            acc[mf][0] = __builtin_amdgcn_mfma_f32_16x16x32_bf16(ah, b0h, acc[mf][0], 0, 0, 0);
            acc[mf][1] = __builtin_amdgcn_mfma_f32_16x16x32_bf16(ah, b1h, acc[mf][1], 0, 0, 0);
            acc[mf][0] = __builtin_amdgcn_mfma_f32_16x16x32_bf16(al, b0h, acc[mf][0], 0, 0, 0);
            acc[mf][1] = __builtin_amdgcn_mfma_f32_16x16x32_bf16(al, b1h, acc[mf][1], 0, 0, 0);
        }
    }

    #pragma unroll
    for (int mf = 0; mf < 4; ++mf)
        #pragma unroll
        for (int j = 0; j < 4; ++j) {
            int ol = mf * 16 + fq * 4 + j;
            float ba = conv_b[o0 + ol];
            float bb = conv_b[512 + o0 + ol];
            float s = 0.f;
            #pragma unroll
            for (int nf = 0; nf < 2; ++nf) {
                float za = acc[mf][nf][j] + ba;
                float zb = acc[mf + 4][nf][j] + bb;
                s += za / (1.f + expf(-zb));
            }
            red[wid][ol][fr] = s;
        }
    __syncthreads();
    if (tid < 64) {
        float s = 0.f;
        #pragma unroll
        for (int w = 0; w < 4; ++w) {
            float4 r0 = *(const float4*)&red[w][tid][0];
            float4 r1 = *(const float4*)&red[w][tid][4];
            float4 r2 = *(const float4*)&red[w][tid][8];
            float4 r3 = *(const float4*)&red[w][tid][12];
            s += (r0.x + r0.y + r0.z + r0.w) + (r1.x + r1.y + r1.z + r1.w)
               + (r2.x + r2.y + r2.z + r2.w) + (r3.x + r3.y + r3.z + r3.w);
        }
        float val = s * dec_w[o0 + tid] * (1.0f / 1024.0f);
        #pragma unroll
        for (int off = 32; off; off >>= 1) val += __shfl_xor(val, off);
        if (tid == 0) partial[((b * 8) + oblk) * 8 + lblk] = val;
    }
}

__global__ void k3_final(const float* __restrict__ partial,
                         const float* __restrict__ dec_b,
                         float* __restrict__ out) {
    int b = threadIdx.x;
    if (b < Bm) {
        float s = dec_b[0];
        for (int i = 0; i < 64; ++i) s += partial[b * 64 + i];
        out[b] = s;
    }
}

extern "C" void kernel_launch(void* const* d_in, const int* in_sizes, int n_in,
                              void* d_out, int out_size, void* d_ws, size_t ws_size,
                              hipStream_t stream) {
    const float* u          = (const float*)d_in[0];
    const float* log_dt     = (const float*)d_in[1];
    const float* log_A_real = (const float*)d_in[2];
    const float* A_imag     = (const float*)d_in[3];
    const float* B_real     = (const float*)d_in[4];
    const float* B_imag     = (const float*)d_in[5];
    const float* C_real     = (const float*)d_in[6];
    const float* C_imag     = (const float*)d_in[7];
    const float* Dvec       = (const float*)d_in[8];
    const float* conv_w     = (const float*)d_in[9];
    const float* conv_b     = (const float*)d_in[10];
    const float* dec_w      = (const float*)d_in[11];
    const float* dec_b      = (const float*)d_in[12];

    char* base = (char*)d_ws;
    unsigned int* Krep   = (unsigned int*)base;                         // 4.5 MB
    unsigned short* YbfH = (unsigned short*)(base + 4718592);           // 8 MB
    unsigned short* Ytb  = (unsigned short*)(base + 13107200);          // 8 MB
    unsigned short* Wh   = (unsigned short*)(base + 21495808);          // 1 MB
    unsigned short* Wl   = (unsigned short*)(base + 22544384);          // 1 MB
    float* partial       = (float*)(base + 23592960);                   // 2 KB
    float* out           = (float*)d_out;

    k_kgen<<<512, 256, 0, stream>>>(log_dt, log_A_real, A_imag, B_real, B_imag,
                                    C_real, C_imag, conv_w, Krep, Wh, Wl);
    k_tconv<<<512, 256, 0, stream>>>(u, Dvec, Krep, YbfH);
    k_tr<<<dim3(16, 8, 8), 256, 0, stream>>>(YbfH, Ytb);
    k2_gemm<<<dim3(8, 8, 8), 256, 0, stream>>>(Wh, Wl, Ytb, conv_b, dec_w, partial);
    k3_final<<<1, 64, 0, stream>>>(partial, dec_b, out);
}

// Round 13
// 61.531 us; speedup vs baseline: 2.2379x; 1.0997x over previous
//
#include <hip/hip_runtime.h>
#include <hip/hip_bf16.h>
#include <math.h>

typedef __attribute__((ext_vector_type(8))) short short8;
typedef __attribute__((ext_vector_type(4))) float f32x4;
typedef __attribute__((ext_vector_type(16))) float f32x16;
typedef __attribute__((ext_vector_type(4))) unsigned int uint4v;

constexpr int Hm = 512, Lm = 1024, Bm = 8;

static __device__ __forceinline__ unsigned short f2bf(float f) {
    __hip_bfloat16 h = __float2bfloat16(f);
    return *reinterpret_cast<unsigned short*>(&h);
}
static __device__ __forceinline__ float bf2f(unsigned short u) {
    return __uint_as_float((unsigned)u << 16);
}
static __device__ __forceinline__ uint2 pack4(const unsigned short* x) {
    return make_uint2((unsigned)x[0] | ((unsigned)x[1] << 16),
                      (unsigned)x[2] | ((unsigned)x[3] << 16));
}
static __device__ __forceinline__ short8 ld16u(const char* p) {   // 2 x b64
    uint2 a = *(const uint2*)p;
    uint2 b = *(const uint2*)(p + 8);
    uint4v t = { a.x, a.y, b.x, b.y };
    return __builtin_bit_cast(short8, t);
}

// K generator + fused param math + fused conv_w bf16 cvt (hi only now).
// Krep per h: 2200 dwords [rep(4)][550]: rep s dword d = bf16-hi of
// (G[2d+s], G[2d+1+s]); G[j]=K[j], zeros past 1023.
__global__ __launch_bounds__(256) void k_kgen(const float* __restrict__ log_dt,
                                              const float* __restrict__ log_A_real,
                                              const float* __restrict__ A_imag,
                                              const float* __restrict__ B_real,
                                              const float* __restrict__ B_imag,
                                              const float* __restrict__ C_real,
                                              const float* __restrict__ C_imag,
                                              const float* __restrict__ conv_w,
                                              unsigned int* __restrict__ Krep,
                                              unsigned short* __restrict__ Woh) {
    __shared__ __align__(16) char smem[22528];   // kl 4x4224 | Kf 4096 | pl 1536
    const int tid = threadIdx.x, lane = tid & 63, wid = tid >> 6;
    float* kl = (float*)smem + wid * 1056;       // [16][66] per wave
    float* Kf = (float*)(smem + 16896);          // [1024]
    float* pl = (float*)(smem + 20992);          // [6][64]
    const int h = blockIdx.x;

    {   // folded conv_w cvt (hi plane only)
        int i = h * 1024 + tid * 4;
        float4 v = *(const float4*)&conv_w[i];
        *(uint2*)&Woh[i] = make_uint2((unsigned)f2bf(v.x) | ((unsigned)f2bf(v.y) << 16),
                                      (unsigned)f2bf(v.z) | ((unsigned)f2bf(v.w) << 16));
    }
    if (tid < 64) {   // folded param math (f64)
        int idx = h * 64 + tid;
        double dt = exp((double)log_dt[h]);
        double Ar = -exp((double)log_A_real[idx]);
        double Ai = (double)A_imag[idx];
        double ar = Ar * dt, ai = Ai * dt;
        double er = exp(ar);
        double rr = er * cos(ai), ri = er * sin(ai);
        double nr = rr - 1.0, ni = ri;
        double den = Ar * Ar + Ai * Ai;
        double qr = (nr * Ar + ni * Ai) / den;
        double qi = (ni * Ar - nr * Ai) / den;
        double Br = (double)B_real[idx], Bi = (double)B_imag[idx];
        double bbr = qr * Br - qi * Bi, bbi = qr * Bi + qi * Br;
        double Cr = (double)C_real[idx], Ci = (double)C_imag[idx];
        double wr = Cr * bbr - Ci * bbi, wi = Cr * bbi + Ci * bbr;
        double e64 = exp(ar * 64.0);
        double p64 = ai * 64.0;
        pl[0 * 64 + tid] = (float)rr;
        pl[1 * 64 + tid] = (float)ri;
        pl[2 * 64 + tid] = (float)wr;
        pl[3 * 64 + tid] = (float)wi;
        pl[4 * 64 + tid] = (float)(e64 * cos(p64));
        pl[5 * 64 + tid] = (float)(e64 * sin(p64));
    }
    __syncthreads();

    const float rrf = pl[0 * 64 + lane], rif = pl[1 * 64 + lane];
    float pr = pl[2 * 64 + lane], pi = pl[3 * 64 + lane];   // w
    float br = pl[4 * 64 + lane], bi = pl[5 * 64 + lane];   // r^64
    int cc = wid * 4;
    while (cc) {   // p = w * (r^64)^(4*wid)
        if (cc & 1) { float t_ = pr * br - pi * bi; pi = fmaf(pr, bi, pi * br); pr = t_; }
        float t2 = br * br - bi * bi; bi = 2.f * br * bi; br = t2;
        cc >>= 1;
    }
    const int jj = lane & 15, nq = lane >> 4;
    for (int q = 0; q < 16; ++q) {
        #pragma unroll
        for (int j = 0; j < 16; ++j) {
            kl[j * 66 + lane] = pr;
            float t_ = pr * rrf - pi * rif; pi = fmaf(pr, rif, pi * rrf); pr = t_;
        }
        asm volatile("s_waitcnt lgkmcnt(0)" ::: "memory");
        float s0 = 0.f, s1 = 0.f;
        #pragma unroll
        for (int n = 0; n < 16; n += 4) {
            float2 a = *(const float2*)&kl[jj * 66 + nq * 16 + n];
            float2 b2 = *(const float2*)&kl[jj * 66 + nq * 16 + n + 2];
            s0 += a.x + a.y; s1 += b2.x + b2.y;
        }
        float s = s0 + s1;
        s += __shfl_xor(s, 16);
        s += __shfl_xor(s, 32);
        if (lane < 16) Kf[wid * 256 + q * 16 + jj] = s;
        asm volatile("s_waitcnt lgkmcnt(0)" ::: "memory");
    }
    __syncthreads();
    for (int t = tid; t < 2200; t += 256) {
        int s = t / 550;
        int d = t - s * 550;
        int idx0 = 2 * d + s;
        float k0 = (idx0 < 1024) ? Kf[idx0] : 0.f;
        float k1 = (idx0 + 1 < 1024) ? Kf[idx0 + 1] : 0.f;
        Krep[(size_t)h * 2200 + t] = (unsigned)f2bf(k0) | ((unsigned)f2bf(k1) << 16);
    }
}

// Toeplitz block-conv, 32x32x16 MFMA, K-hi only, 4 waves x 1 tile (R12-proven).
__global__ __launch_bounds__(256, 2) void k_tconv(const float* __restrict__ u,
                                                  const float* __restrict__ Dvec,
                                                  const unsigned int* __restrict__ Krep,
                                                  unsigned short* __restrict__ YbfH) {
    __shared__ __align__(16) char smem[36160];
    const int tid = threadIdx.x, lane = tid & 63, w = tid >> 6;   // 4 waves
    const int h = blockIdx.x;
    const int m = lane & 31, q = lane >> 5;
    const int cg = (lane >> 3) & 3, b = lane & 7;

    {   // stage G hi replicas (550 uint4)
        const uint4* src = (const uint4*)(Krep + (size_t)h * 2200);
        uint4* dst = (uint4*)smem;
        for (int o = tid; o < 550; o += 256) dst[o] = src[o];
    }
    if (tid < 8) { uint4 z = {0, 0, 0, 0}; ((uint4*)(smem + 36032))[tid] = z; }
    {   // stage u -> [jc][b][72] bf16
        const int b2 = tid >> 5, t32 = tid & 31;
        const float* ub = u + ((size_t)(b2 * 512 + h)) * 1024;
        #pragma unroll
        for (int g = 0; g < 8; ++g) {
            int s = t32 * 4 + g * 128;
            float4 v = *(const float4*)&ub[s];
            unsigned short t0 = f2bf(v.x), t1 = f2bf(v.y), t2 = f2bf(v.z), t3 = f2bf(v.w);
            int jc = s >> 6, e = s & 63;
            *(uint2*)(smem + 17600 + jc * 1152 + b2 * 144 + e * 2) =
                make_uint2((unsigned)t0 | ((unsigned)t1 << 16),
                           (unsigned)t2 | ((unsigned)t3 << 16));
        }
    }
    __syncthreads();

    const int icg = (cg == 0) ? w : (cg == 1) ? 7 - w : (cg == 2) ? 8 + w : 15 - w;
    const int dmax = 15 - w;

    int aU = 17600 + icg * 1152 + b * 144 + q * 16;
    const int zl = 36032 + q * 16;

    const int r = (3 - m) & 3;
    int baseH = r * 2200 + (991 - m - r + 8 * q) * 2;

    const f32x16 zacc = {};
    f32x16 acc0 = zacc, acc1 = zacc;

    short8 m2, m1, w0, w1, w2, w3;
    {
        const char* pH = smem + baseH;
        m2 = ld16u(pH +   0); m1 = ld16u(pH +  32);
        w0 = ld16u(pH +  64); w1 = ld16u(pH +  96);
        w2 = ld16u(pH + 128); w3 = ld16u(pH + 160);
    }

    for (int d = 0; d <= dmax; ++d) {
        const char* pb = smem + ((d <= icg) ? aU : zl);
        short8 b0 = *(const short8*)(pb +  0);
        short8 b1 = *(const short8*)(pb + 32);
        short8 b2 = *(const short8*)(pb + 64);
        short8 b3 = *(const short8*)(pb + 96);
        acc0 = __builtin_amdgcn_mfma_f32_32x32x16_bf16(w0, b0, acc0, 0, 0, 0);
        acc1 = __builtin_amdgcn_mfma_f32_32x32x16_bf16(m2, b0, acc1, 0, 0, 0);
        acc0 = __builtin_amdgcn_mfma_f32_32x32x16_bf16(w1, b1, acc0, 0, 0, 0);
        acc1 = __builtin_amdgcn_mfma_f32_32x32x16_bf16(m1, b1, acc1, 0, 0, 0);
        acc0 = __builtin_amdgcn_mfma_f32_32x32x16_bf16(w2, b2, acc0, 0, 0, 0);
        acc1 = __builtin_amdgcn_mfma_f32_32x32x16_bf16(w0, b2, acc1, 0, 0, 0);
        acc0 = __builtin_amdgcn_mfma_f32_32x32x16_bf16(w3, b3, acc0, 0, 0, 0);
        acc1 = __builtin_amdgcn_mfma_f32_32x32x16_bf16(w1, b3, acc1, 0, 0, 0);
        baseH -= 128; aU -= 1152;
        if (d < dmax) {
            const char* pH = smem + baseH;
            m2 = ld16u(pH +   0); m1 = ld16u(pH +  32);
            w0 = ld16u(pH +  64); w1 = ld16u(pH +  96);
            w2 = ld16u(pH + 128); w3 = ld16u(pH + 160);
        }
    }

    const float Dh = Dvec[h];
    __syncthreads();   // G region dead -> Y bounce [16][8][68]

    #pragma unroll
    for (int mf = 0; mf < 2; ++mf) {
        const f32x16 ac = mf ? acc1 : acc0;
        #pragma unroll
        for (int rq = 0; rq < 4; ++rq) {
            const int row0 = mf * 32 + 8 * rq + 4 * q;
            uint2 uv2 = *(const uint2*)(smem + 17600 + icg * 1152 + b * 144 + row0 * 2);
            unsigned short us[4] = { (unsigned short)(uv2.x & 0xffff),
                                     (unsigned short)(uv2.x >> 16),
                                     (unsigned short)(uv2.y & 0xffff),
                                     (unsigned short)(uv2.y >> 16) };
            unsigned short oh[4];
            #pragma unroll
            for (int k = 0; k < 4; ++k) {
                float y = ac[rq * 4 + k] + Dh * bf2f(us[k]);
                float g = 0.5f * y * (1.0f + erff(y * 0.70710678118654752f));
                oh[k] = f2bf(g);
            }
            *(uint2*)(smem + icg * 1088 + b * 136 + row0 * 2) = pack4(oh);
        }
    }
    __syncthreads();
    {   // coalesced copy-out: Ybf[b][h][l]
        const int b2 = tid >> 5, t32 = tid & 31;
        unsigned short* dst = YbfH + ((size_t)(b2 * 512 + h)) * 1024;
        #pragma unroll
        for (int g = 0; g < 8; ++g) {
            int s = t32 * 4 + g * 128;
            int jc = s >> 6, e = s & 63;
            uint2 v = *(const uint2*)(smem + jc * 1088 + b2 * 136 + e * 2);
            *(uint2*)&dst[s] = v;
        }
    }
}

// W-hi-only bf16 MFMA GEMM with FUSED Y transpose (consumes Ybf[b][c][l]
// directly; k_tr eliminated) + bias/GLU/pool/dec epilogue.
// YT[128 l][44] bf16: stride 88B -> b32 writes 2-way (free), b64 reads
// hit 16 distinct banks (22*fr mod 32 all distinct).
__global__ __launch_bounds__(256) void k2_gemm(const unsigned short* __restrict__ WbfH,
                                               const unsigned short* __restrict__ Ybf,
                                               const float* __restrict__ conv_b,
                                               const float* __restrict__ dec_w,
                                               float* __restrict__ partial) {
    __shared__ unsigned short WTh[128][40];
    __shared__ unsigned short YT[128][44];
    __shared__ float red[4][64][20];
    const int tid = threadIdx.x, lane = tid & 63, wid = tid >> 6;
    const int b = blockIdx.z, oblk = blockIdx.y, lblk = blockIdx.x;
    const int o0 = oblk * 64, l0 = lblk * 128;
    const int fr = lane & 15, fq = lane >> 4;

    f32x4 acc[8][2] = {};

    const int srow = tid >> 1, skh = (tid & 1) * 16;
    const int grow = (srow < 64) ? (o0 + srow) : (512 + o0 + srow - 64);
    const size_t woff = (size_t)grow * 512 + skh;
    const int cp = tid & 15, lg = tid >> 4;   // y-transpose: c-pair, l-group

    for (int c0 = 0; c0 < 512; c0 += 32) {
        __syncthreads();
        uint4 wh0 = *(const uint4*)(WbfH + woff + c0);
        uint4 wh1 = *(const uint4*)(WbfH + woff + c0 + 8);
        const unsigned short* ys0 = Ybf + ((size_t)(b * 512 + c0 + 2 * cp)) * 1024 + l0 + lg * 8;
        uint4 y0 = *(const uint4*)ys0;            // 8 l of even c
        uint4 y1 = *(const uint4*)(ys0 + 1024);   // 8 l of odd c
        *(uint4*)&WTh[srow][skh]     = wh0;
        *(uint4*)&WTh[srow][skh + 8] = wh1;
        {   // transpose-pack: YT[l][2cp..2cp+1]
            const unsigned int* a = (const unsigned int*)&y0;
            const unsigned int* c = (const unsigned int*)&y1;
            #pragma unroll
            for (int t2 = 0; t2 < 4; ++t2) {
                unsigned int lo = (a[t2] & 0xffffu) | (c[t2] << 16);
                unsigned int hi = (a[t2] >> 16) | (c[t2] & 0xffff0000u);
                *(unsigned int*)&YT[lg * 8 + 2 * t2][2 * cp] = lo;
                *(unsigned int*)&YT[lg * 8 + 2 * t2 + 1][2 * cp] = hi;
            }
        }
        __syncthreads();
        short8 b0h = ld16u((const char*)&YT[wid * 32 + fr][fq * 8]);
        short8 b1h = ld16u((const char*)&YT[wid * 32 + 16 + fr][fq * 8]);
        #pragma unroll
        for (int mf = 0; mf < 8; ++mf) {
            short8 ah = *(const short8*)&WTh[mf * 16 + fr][fq * 8];
            acc[mf][0] = __builtin_amdgcn_mfma_f32_16x16x32_bf16(ah, b0h, acc[mf][0], 0, 0, 0);
            acc[mf][1] = __builtin_amdgcn_mfma_f32_16x16x32_bf16(ah, b1h, acc[mf][1], 0, 0, 0);
        }
    }

    #pragma unroll
    for (int mf = 0; mf < 4; ++mf)
        #pragma unroll
        for (int j = 0; j < 4; ++j) {
            int ol = mf * 16 + fq * 4 + j;
            float ba = conv_b[o0 + ol];
            float bb = conv_b[512 + o0 + ol];
            float s = 0.f;
            #pragma unroll
            for (int nf = 0; nf < 2; ++nf) {
                float za = acc[mf][nf][j] + ba;
                float zb = acc[mf + 4][nf][j] + bb;
                s += za / (1.f + expf(-zb));
            }
            red[wid][ol][fr] = s;
        }
    __syncthreads();
    if (tid < 64) {
        float s = 0.f;
        #pragma unroll
        for (int w = 0; w < 4; ++w) {
            float4 r0 = *(const float4*)&red[w][tid][0];
            float4 r1 = *(const float4*)&red[w][tid][4];
            float4 r2 = *(const float4*)&red[w][tid][8];
            float4 r3 = *(const float4*)&red[w][tid][12];
            s += (r0.x + r0.y + r0.z + r0.w) + (r1.x + r1.y + r1.z + r1.w)
               + (r2.x + r2.y + r2.z + r2.w) + (r3.x + r3.y + r3.z + r3.w);
        }
        float val = s * dec_w[o0 + tid] * (1.0f / 1024.0f);
        #pragma unroll
        for (int off = 32; off; off >>= 1) val += __shfl_xor(val, off);
        if (tid == 0) partial[((b * 8) + oblk) * 8 + lblk] = val;
    }
}

__global__ void k3_final(const float* __restrict__ partial,
                         const float* __restrict__ dec_b,
                         float* __restrict__ out) {
    int b = threadIdx.x;
    if (b < Bm) {
        float s = dec_b[0];
        for (int i = 0; i < 64; ++i) s += partial[b * 64 + i];
        out[b] = s;
    }
}

extern "C" void kernel_launch(void* const* d_in, const int* in_sizes, int n_in,
                              void* d_out, int out_size, void* d_ws, size_t ws_size,
                              hipStream_t stream) {
    const float* u          = (const float*)d_in[0];
    const float* log_dt     = (const float*)d_in[1];
    const float* log_A_real = (const float*)d_in[2];
    const float* A_imag     = (const float*)d_in[3];
    const float* B_real     = (const float*)d_in[4];
    const float* B_imag     = (const float*)d_in[5];
    const float* C_real     = (const float*)d_in[6];
    const float* C_imag     = (const float*)d_in[7];
    const float* Dvec       = (const float*)d_in[8];
    const float* conv_w     = (const float*)d_in[9];
    const float* conv_b     = (const float*)d_in[10];
    const float* dec_w      = (const float*)d_in[11];
    const float* dec_b      = (const float*)d_in[12];

    char* base = (char*)d_ws;
    unsigned int* Krep   = (unsigned int*)base;                         // 4.5 MB
    unsigned short* YbfH = (unsigned short*)(base + 4718592);           // 8 MB
    unsigned short* Wh   = (unsigned short*)(base + 13107200);          // 1 MB
    float* partial       = (float*)(base + 14155776);                   // 2 KB
    float* out           = (float*)d_out;

    k_kgen<<<512, 256, 0, stream>>>(log_dt, log_A_real, A_imag, B_real, B_imag,
                                    C_real, C_imag, conv_w, Krep, Wh);
    k_tconv<<<512, 256, 0, stream>>>(u, Dvec, Krep, YbfH);
    k2_gemm<<<dim3(8, 8, 8), 256, 0, stream>>>(Wh, YbfH, conv_b, dec_w, partial);
    k3_final<<<1, 64, 0, stream>>>(partial, dec_b, out);
}

// Round 14
// 56.612 us; speedup vs baseline: 2.4324x; 1.0869x over previous
//
#include <hip/hip_runtime.h>
#include <hip/hip_bf16.h>
#include <math.h>

typedef __attribute__((ext_vector_type(8))) short short8;
typedef __attribute__((ext_vector_type(4))) float f32x4;
typedef __attribute__((ext_vector_type(16))) float f32x16;
typedef __attribute__((ext_vector_type(4))) unsigned int uint4v;

constexpr int Hm = 512, Lm = 1024, Bm = 8;

static __device__ __forceinline__ unsigned short f2bf(float f) {
    __hip_bfloat16 h = __float2bfloat16(f);
    return *reinterpret_cast<unsigned short*>(&h);
}
static __device__ __forceinline__ float bf2f(unsigned short u) {
    return __uint_as_float((unsigned)u << 16);
}
static __device__ __forceinline__ uint2 pack4(const unsigned short* x) {
    return make_uint2((unsigned)x[0] | ((unsigned)x[1] << 16),
                      (unsigned)x[2] | ((unsigned)x[3] << 16));
}
static __device__ __forceinline__ short8 ld16u(const char* p) {   // 2 x b64
    uint2 a = *(const uint2*)p;
    uint2 b = *(const uint2*)(p + 8);
    uint4v t = { a.x, a.y, b.x, b.y };
    return __builtin_bit_cast(short8, t);
}

// FUSED: param math (f64) + K generation + conv_w cvt + Toeplitz block-conv.
// One block per h (256 thr, 4 waves). K computed in-LDS (no Krep global).
// LDS map (36160 B):
//   G   [0, 8800)      [rep4][1100] bf16-hi replicas: G[e+s]=K[e+s], 0 past 1023
//   Kf  [8800, 12896)  f32[1024]
//   pl  [12896, 14432) f32[6][64] params
//   u   [17600, 36032) [16jc][8b][72us]   (phase-0 kl scratch overlays this)
//   zl  [36032, 36160) zero tile
__global__ __launch_bounds__(256, 2) void k_tconv(const float* __restrict__ log_dt,
                                                  const float* __restrict__ log_A_real,
                                                  const float* __restrict__ A_imag,
                                                  const float* __restrict__ B_real,
                                                  const float* __restrict__ B_imag,
                                                  const float* __restrict__ C_real,
                                                  const float* __restrict__ C_imag,
                                                  const float* __restrict__ conv_w,
                                                  const float* __restrict__ u,
                                                  const float* __restrict__ Dvec,
                                                  unsigned short* __restrict__ Woh,
                                                  unsigned short* __restrict__ YbfH) {
    __shared__ __align__(16) char smem[36160];
    const int tid = threadIdx.x, lane = tid & 63, w = tid >> 6;   // 4 waves
    const int h = blockIdx.x;
    const int m = lane & 31, q = lane >> 5;
    const int cg = (lane >> 3) & 3, b = lane & 7;
    float* Kf = (float*)(smem + 8800);    // [1024]
    float* pl = (float*)(smem + 12896);   // [6][64]

    {   // conv_w bf16 cvt (hi only): this block converts 1024 floats
        int i = h * 1024 + tid * 4;
        float4 v = *(const float4*)&conv_w[i];
        *(uint2*)&Woh[i] = make_uint2((unsigned)f2bf(v.x) | ((unsigned)f2bf(v.y) << 16),
                                      (unsigned)f2bf(v.z) | ((unsigned)f2bf(v.w) << 16));
    }
    if (tid < 64) {   // param math (f64)
        int idx = h * 64 + tid;
        double dt = exp((double)log_dt[h]);
        double Ar = -exp((double)log_A_real[idx]);
        double Ai = (double)A_imag[idx];
        double ar = Ar * dt, ai = Ai * dt;
        double er = exp(ar);
        double rr = er * cos(ai), ri = er * sin(ai);
        double nr = rr - 1.0, ni = ri;
        double den = Ar * Ar + Ai * Ai;
        double qr = (nr * Ar + ni * Ai) / den;
        double qi = (ni * Ar - nr * Ai) / den;
        double Br = (double)B_real[idx], Bi = (double)B_imag[idx];
        double bbr = qr * Br - qi * Bi, bbi = qr * Bi + qi * Br;
        double Cr = (double)C_real[idx], Ci = (double)C_imag[idx];
        double wr = Cr * bbr - Ci * bbi, wi = Cr * bbi + Ci * bbr;
        double e64 = exp(ar * 64.0);
        double p64 = ai * 64.0;
        pl[0 * 64 + tid] = (float)rr;
        pl[1 * 64 + tid] = (float)ri;
        pl[2 * 64 + tid] = (float)wr;
        pl[3 * 64 + tid] = (float)wi;
        pl[4 * 64 + tid] = (float)(e64 * cos(p64));
        pl[5 * 64 + tid] = (float)(e64 * sin(p64));
    }
    __syncthreads();

    {   // K rotation: Kf[j] = Re(sum_n w_n r_n^j); kl scratch overlays u region
        float* kl = (float*)(smem + 17600) + w * 1056;   // [16][66] per wave
        const float rrf = pl[0 * 64 + lane], rif = pl[1 * 64 + lane];
        float pr = pl[2 * 64 + lane], pi = pl[3 * 64 + lane];   // w
        float br = pl[4 * 64 + lane], bi = pl[5 * 64 + lane];   // r^64
        int cc = w * 4;
        while (cc) {   // p = w * (r^64)^(4*wid)
            if (cc & 1) { float t_ = pr * br - pi * bi; pi = fmaf(pr, bi, pi * br); pr = t_; }
            float t2 = br * br - bi * bi; bi = 2.f * br * bi; br = t2;
            cc >>= 1;
        }
        const int jj = lane & 15, nq = lane >> 4;
        for (int qq = 0; qq < 16; ++qq) {
            #pragma unroll
            for (int j = 0; j < 16; ++j) {
                kl[j * 66 + lane] = pr;
                float t_ = pr * rrf - pi * rif; pi = fmaf(pr, rif, pi * rrf); pr = t_;
            }
            asm volatile("s_waitcnt lgkmcnt(0)" ::: "memory");
            float s0 = 0.f, s1 = 0.f;
            #pragma unroll
            for (int n = 0; n < 16; n += 4) {
                float2 a = *(const float2*)&kl[jj * 66 + nq * 16 + n];
                float2 b2 = *(const float2*)&kl[jj * 66 + nq * 16 + n + 2];
                s0 += a.x + a.y; s1 += b2.x + b2.y;
            }
            float s = s0 + s1;
            s += __shfl_xor(s, 16);
            s += __shfl_xor(s, 32);
            if (lane < 16) Kf[w * 256 + qq * 16 + jj] = s;
            asm volatile("s_waitcnt lgkmcnt(0)" ::: "memory");
        }
    }
    __syncthreads();

    {   // pack Kf -> G bf16 replicas (in-LDS): dword s*550+d = (K[2d+s],K[2d+1+s])
        unsigned int* Gd = (unsigned int*)smem;
        for (int t = tid; t < 2200; t += 256) {
            int s = t / 550;
            int d = t - s * 550;
            int idx0 = 2 * d + s;
            float k0 = (idx0 < 1024) ? Kf[idx0] : 0.f;
            float k1 = (idx0 + 1 < 1024) ? Kf[idx0 + 1] : 0.f;
            Gd[t] = (unsigned)f2bf(k0) | ((unsigned)f2bf(k1) << 16);
        }
    }
    if (tid < 8) { uint4 z = {0, 0, 0, 0}; ((uint4*)(smem + 36032))[tid] = z; }
    __syncthreads();

    {   // stage u -> [jc][b][72] bf16 (overwrites kl scratch)
        const int b2 = tid >> 5, t32 = tid & 31;
        const float* ub = u + ((size_t)(b2 * 512 + h)) * 1024;
        #pragma unroll
        for (int g = 0; g < 8; ++g) {
            int s = t32 * 4 + g * 128;
            float4 v = *(const float4*)&ub[s];
            unsigned short t0 = f2bf(v.x), t1 = f2bf(v.y), t2 = f2bf(v.z), t3 = f2bf(v.w);
            int jc = s >> 6, e = s & 63;
            *(uint2*)(smem + 17600 + jc * 1152 + b2 * 144 + e * 2) =
                make_uint2((unsigned)t0 | ((unsigned)t1 << 16),
                           (unsigned)t2 | ((unsigned)t3 << 16));
        }
    }
    __syncthreads();

    const int icg = (cg == 0) ? w : (cg == 1) ? 7 - w : (cg == 2) ? 8 + w : 15 - w;
    const int dmax = 15 - w;

    int aU = 17600 + icg * 1152 + b * 144 + q * 16;
    const int zl = 36032 + q * 16;

    const int r = (3 - m) & 3;
    int baseH = r * 2200 + (991 - m - r + 8 * q) * 2;

    const f32x16 zacc = {};
    f32x16 acc0 = zacc, acc1 = zacc;

    short8 m2, m1, w0, w1, w2, w3;
    {
        const char* pH = smem + baseH;
        m2 = ld16u(pH +   0); m1 = ld16u(pH +  32);
        w0 = ld16u(pH +  64); w1 = ld16u(pH +  96);
        w2 = ld16u(pH + 128); w3 = ld16u(pH + 160);
    }

    for (int d = 0; d <= dmax; ++d) {
        const char* pb = smem + ((d <= icg) ? aU : zl);
        short8 b0 = *(const short8*)(pb +  0);
        short8 b1 = *(const short8*)(pb + 32);
        short8 b2 = *(const short8*)(pb + 64);
        short8 b3 = *(const short8*)(pb + 96);
        acc0 = __builtin_amdgcn_mfma_f32_32x32x16_bf16(w0, b0, acc0, 0, 0, 0);
        acc1 = __builtin_amdgcn_mfma_f32_32x32x16_bf16(m2, b0, acc1, 0, 0, 0);
        acc0 = __builtin_amdgcn_mfma_f32_32x32x16_bf16(w1, b1, acc0, 0, 0, 0);
        acc1 = __builtin_amdgcn_mfma_f32_32x32x16_bf16(m1, b1, acc1, 0, 0, 0);
        acc0 = __builtin_amdgcn_mfma_f32_32x32x16_bf16(w2, b2, acc0, 0, 0, 0);
        acc1 = __builtin_amdgcn_mfma_f32_32x32x16_bf16(w0, b2, acc1, 0, 0, 0);
        acc0 = __builtin_amdgcn_mfma_f32_32x32x16_bf16(w3, b3, acc0, 0, 0, 0);
        acc1 = __builtin_amdgcn_mfma_f32_32x32x16_bf16(w1, b3, acc1, 0, 0, 0);
        baseH -= 128; aU -= 1152;
        if (d < dmax) {
            const char* pH = smem + baseH;
            m2 = ld16u(pH +   0); m1 = ld16u(pH +  32);
            w0 = ld16u(pH +  64); w1 = ld16u(pH +  96);
            w2 = ld16u(pH + 128); w3 = ld16u(pH + 160);
        }
    }

    const float Dh = Dvec[h];
    __syncthreads();   // G region dead -> Y bounce [16][8][68]

    #pragma unroll
    for (int mf = 0; mf < 2; ++mf) {
        const f32x16 ac = mf ? acc1 : acc0;
        #pragma unroll
        for (int rq = 0; rq < 4; ++rq) {
            const int row0 = mf * 32 + 8 * rq + 4 * q;
            uint2 uv2 = *(const uint2*)(smem + 17600 + icg * 1152 + b * 144 + row0 * 2);
            unsigned short us[4] = { (unsigned short)(uv2.x & 0xffff),
                                     (unsigned short)(uv2.x >> 16),
                                     (unsigned short)(uv2.y & 0xffff),
                                     (unsigned short)(uv2.y >> 16) };
            unsigned short oh[4];
            #pragma unroll
            for (int k = 0; k < 4; ++k) {
                float y = ac[rq * 4 + k] + Dh * bf2f(us[k]);
                float g = 0.5f * y * (1.0f + erff(y * 0.70710678118654752f));
                oh[k] = f2bf(g);
            }
            *(uint2*)(smem + icg * 1088 + b * 136 + row0 * 2) = pack4(oh);
        }
    }
    __syncthreads();
    {   // coalesced copy-out: Ybf[b][h][l]
        const int b2 = tid >> 5, t32 = tid & 31;
        unsigned short* dst = YbfH + ((size_t)(b2 * 512 + h)) * 1024;
        #pragma unroll
        for (int g = 0; g < 8; ++g) {
            int s = t32 * 4 + g * 128;
            int jc = s >> 6, e = s & 63;
            uint2 v = *(const uint2*)(smem + jc * 1088 + b2 * 136 + e * 2);
            *(uint2*)&dst[s] = v;
        }
    }
}

// W-hi-only bf16 MFMA GEMM with fused Y transpose + bias/GLU/pool/dec epilogue.
__global__ __launch_bounds__(256) void k2_gemm(const unsigned short* __restrict__ WbfH,
                                               const unsigned short* __restrict__ Ybf,
                                               const float* __restrict__ conv_b,
                                               const float* __restrict__ dec_w,
                                               float* __restrict__ partial) {
    __shared__ unsigned short WTh[128][40];
    __shared__ unsigned short YT[128][44];
    __shared__ float red[4][64][20];
    const int tid = threadIdx.x, lane = tid & 63, wid = tid >> 6;
    const int b = blockIdx.z, oblk = blockIdx.y, lblk = blockIdx.x;
    const int o0 = oblk * 64, l0 = lblk * 128;
    const int fr = lane & 15, fq = lane >> 4;

    f32x4 acc[8][2] = {};

    const int srow = tid >> 1, skh = (tid & 1) * 16;
    const int grow = (srow < 64) ? (o0 + srow) : (512 + o0 + srow - 64);
    const size_t woff = (size_t)grow * 512 + skh;
    const int cp = tid & 15, lg = tid >> 4;

    for (int c0 = 0; c0 < 512; c0 += 32) {
        __syncthreads();
        uint4 wh0 = *(const uint4*)(WbfH + woff + c0);
        uint4 wh1 = *(const uint4*)(WbfH + woff + c0 + 8);
        const unsigned short* ys0 = Ybf + ((size_t)(b * 512 + c0 + 2 * cp)) * 1024 + l0 + lg * 8;
        uint4 y0 = *(const uint4*)ys0;
        uint4 y1 = *(const uint4*)(ys0 + 1024);
        *(uint4*)&WTh[srow][skh]     = wh0;
        *(uint4*)&WTh[srow][skh + 8] = wh1;
        {
            const unsigned int* a = (const unsigned int*)&y0;
            const unsigned int* c = (const unsigned int*)&y1;
            #pragma unroll
            for (int t2 = 0; t2 < 4; ++t2) {
                unsigned int lo = (a[t2] & 0xffffu) | (c[t2] << 16);
                unsigned int hi = (a[t2] >> 16) | (c[t2] & 0xffff0000u);
                *(unsigned int*)&YT[lg * 8 + 2 * t2][2 * cp] = lo;
                *(unsigned int*)&YT[lg * 8 + 2 * t2 + 1][2 * cp] = hi;
            }
        }
        __syncthreads();
        short8 b0h = ld16u((const char*)&YT[wid * 32 + fr][fq * 8]);
        short8 b1h = ld16u((const char*)&YT[wid * 32 + 16 + fr][fq * 8]);
        #pragma unroll
        for (int mf = 0; mf < 8; ++mf) {
            short8 ah = *(const short8*)&WTh[mf * 16 + fr][fq * 8];
            acc[mf][0] = __builtin_amdgcn_mfma_f32_16x16x32_bf16(ah, b0h, acc[mf][0], 0, 0, 0);
            acc[mf][1] = __builtin_amdgcn_mfma_f32_16x16x32_bf16(ah, b1h, acc[mf][1], 0, 0, 0);
        }
    }

    #pragma unroll
    for (int mf = 0; mf < 4; ++mf)
        #pragma unroll
        for (int j = 0; j < 4; ++j) {
            int ol = mf * 16 + fq * 4 + j;
            float ba = conv_b[o0 + ol];
            float bb = conv_b[512 + o0 + ol];
            float s = 0.f;
            #pragma unroll
            for (int nf = 0; nf < 2; ++nf) {
                float za = acc[mf][nf][j] + ba;
                float zb = acc[mf + 4][nf][j] + bb;
                s += za / (1.f + expf(-zb));
            }
            red[wid][ol][fr] = s;
        }
    __syncthreads();
    if (tid < 64) {
        float s = 0.f;
        #pragma unroll
        for (int w = 0; w < 4; ++w) {
            float4 r0 = *(const float4*)&red[w][tid][0];
            float4 r1 = *(const float4*)&red[w][tid][4];
            float4 r2 = *(const float4*)&red[w][tid][8];
            float4 r3 = *(const float4*)&red[w][tid][12];
            s += (r0.x + r0.y + r0.z + r0.w) + (r1.x + r1.y + r1.z + r1.w)
               + (r2.x + r2.y + r2.z + r2.w) + (r3.x + r3.y + r3.z + r3.w);
        }
        float val = s * dec_w[o0 + tid] * (1.0f / 1024.0f);
        #pragma unroll
        for (int off = 32; off; off >>= 1) val += __shfl_xor(val, off);
        if (tid == 0) partial[((b * 8) + oblk) * 8 + lblk] = val;
    }
}

__global__ void k3_final(const float* __restrict__ partial,
                         const float* __restrict__ dec_b,
                         float* __restrict__ out) {
    int b = threadIdx.x;
    if (b < Bm) {
        float s = dec_b[0];
        for (int i = 0; i < 64; ++i) s += partial[b * 64 + i];
        out[b] = s;
    }
}

extern "C" void kernel_launch(void* const* d_in, const int* in_sizes, int n_in,
                              void* d_out, int out_size, void* d_ws, size_t ws_size,
                              hipStream_t stream) {
    const float* u          = (const float*)d_in[0];
    const float* log_dt     = (const float*)d_in[1];
    const float* log_A_real = (const float*)d_in[2];
    const float* A_imag     = (const float*)d_in[3];
    const float* B_real     = (const float*)d_in[4];
    const float* B_imag     = (const float*)d_in[5];
    const float* C_real     = (const float*)d_in[6];
    const float* C_imag     = (const float*)d_in[7];
    const float* Dvec       = (const float*)d_in[8];
    const float* conv_w     = (const float*)d_in[9];
    const float* conv_b     = (const float*)d_in[10];
    const float* dec_w      = (const float*)d_in[11];
    const float* dec_b      = (const float*)d_in[12];

    char* base = (char*)d_ws;
    unsigned short* YbfH = (unsigned short*)base;                       // 8 MB
    unsigned short* Wh   = (unsigned short*)(base + 8388608);           // 1 MB
    float* partial       = (float*)(base + 9437184);                    // 2 KB
    float* out           = (float*)d_out;

    k_tconv<<<512, 256, 0, stream>>>(log_dt, log_A_real, A_imag, B_real, B_imag,
                                     C_real, C_imag, conv_w, u, Dvec, Wh, YbfH);
    k2_gemm<<<dim3(8, 8, 8), 256, 0, stream>>>(Wh, YbfH, conv_b, dec_w, partial);
    k3_final<<<1, 64, 0, stream>>>(partial, dec_b, out);
}

// Round 15
// 54.901 us; speedup vs baseline: 2.5082x; 1.0312x over previous
//
#include <hip/hip_runtime.h>
#include <hip/hip_bf16.h>
#include <math.h>

typedef __attribute__((ext_vector_type(8))) short short8;
typedef __attribute__((ext_vector_type(4))) float f32x4;
typedef __attribute__((ext_vector_type(16))) float f32x16;
typedef __attribute__((ext_vector_type(4))) unsigned int uint4v;

constexpr int Hm = 512, Lm = 1024, Bm = 8;

static __device__ __forceinline__ unsigned short f2bf(float f) {
    __hip_bfloat16 h = __float2bfloat16(f);
    return *reinterpret_cast<unsigned short*>(&h);
}
static __device__ __forceinline__ float bf2f(unsigned short u) {
    return __uint_as_float((unsigned)u << 16);
}
static __device__ __forceinline__ uint2 pack4(const unsigned short* x) {
    return make_uint2((unsigned)x[0] | ((unsigned)x[1] << 16),
                      (unsigned)x[2] | ((unsigned)x[3] << 16));
}
static __device__ __forceinline__ short8 ld16u(const char* p) {   // 2 x b64
    uint2 a = *(const uint2*)p;
    uint2 b = *(const uint2*)(p + 8);
    uint4v t = { a.x, a.y, b.x, b.y };
    return __builtin_bit_cast(short8, t);
}

// FUSED: param math (f64) + K generation + conv_w cvt + Toeplitz block-conv.
// One block per h (256 thr, 4 waves).
// G: bf16-hi K with 8 shifted replicas, stride 1112 elems (2224 B, 16B-mult):
//   replica s dword d = (K[2d+s], K[2d+1+s]), d < 556, zeros past K[1023].
//   elem i of replica s lives at byte s*2224 + 2*(i-s).
// LDS map (41984 B):
//   G   [0, 17792)
//   u   [17792, 36224)  [16jc][8b][72us]  (rotation kl scratch overlays this)
//   zl  [36224, 36352)  zero tile
//   Kf  [36352, 40448)  f32[1024]
//   pl  [40448, 41984)  f32[6][64]
//   Y-bounce reuses [0,17408) after d-loop.
__global__ __launch_bounds__(256, 2) void k_tconv(const float* __restrict__ log_dt,
                                                  const float* __restrict__ log_A_real,
                                                  const float* __restrict__ A_imag,
                                                  const float* __restrict__ B_real,
                                                  const float* __restrict__ B_imag,
                                                  const float* __restrict__ C_real,
                                                  const float* __restrict__ C_imag,
                                                  const float* __restrict__ conv_w,
                                                  const float* __restrict__ u,
                                                  const float* __restrict__ Dvec,
                                                  unsigned short* __restrict__ Woh,
                                                  unsigned short* __restrict__ YbfH) {
    __shared__ __align__(16) char smem[41984];
    const int tid = threadIdx.x, lane = tid & 63, w = tid >> 6;   // 4 waves
    const int h = blockIdx.x;
    const int m = lane & 31, q = lane >> 5;
    const int cg = (lane >> 3) & 3, b = lane & 7;
    float* Kf = (float*)(smem + 36352);   // [1024]
    float* pl = (float*)(smem + 40448);   // [6][64]

    // T14: issue u loads EARLY (held in regs across the rotation phase)
    float4 ureg[8];
    {
        const int b2 = tid >> 5, t32 = tid & 31;
        const float* ub = u + ((size_t)(b2 * 512 + h)) * 1024;
        #pragma unroll
        for (int g = 0; g < 8; ++g) ureg[g] = *(const float4*)&ub[t32 * 4 + g * 128];
    }
    const float Dh = Dvec[h];

    {   // conv_w bf16 cvt (hi only): this block converts 1024 floats
        int i = h * 1024 + tid * 4;
        float4 v = *(const float4*)&conv_w[i];
        *(uint2*)&Woh[i] = make_uint2((unsigned)f2bf(v.x) | ((unsigned)f2bf(v.y) << 16),
                                      (unsigned)f2bf(v.z) | ((unsigned)f2bf(v.w) << 16));
    }
    if (tid < 64) {   // param math (f64)
        int idx = h * 64 + tid;
        double dt = exp((double)log_dt[h]);
        double Ar = -exp((double)log_A_real[idx]);
        double Ai = (double)A_imag[idx];
        double ar = Ar * dt, ai = Ai * dt;
        double er = exp(ar);
        double rr = er * cos(ai), ri = er * sin(ai);
        double nr = rr - 1.0, ni = ri;
        double den = Ar * Ar + Ai * Ai;
        double qr = (nr * Ar + ni * Ai) / den;
        double qi = (ni * Ar - nr * Ai) / den;
        double Br = (double)B_real[idx], Bi = (double)B_imag[idx];
        double bbr = qr * Br - qi * Bi, bbi = qr * Bi + qi * Br;
        double Cr = (double)C_real[idx], Ci = (double)C_imag[idx];
        double wr = Cr * bbr - Ci * bbi, wi = Cr * bbi + Ci * bbr;
        double e64 = exp(ar * 64.0);
        double p64 = ai * 64.0;
        pl[0 * 64 + tid] = (float)rr;
        pl[1 * 64 + tid] = (float)ri;
        pl[2 * 64 + tid] = (float)wr;
        pl[3 * 64 + tid] = (float)wi;
        pl[4 * 64 + tid] = (float)(e64 * cos(p64));
        pl[5 * 64 + tid] = (float)(e64 * sin(p64));
    }
    __syncthreads();

    {   // K rotation: Kf[j] = Re(sum_n w_n r_n^j); kl scratch overlays u region
        float* kl = (float*)(smem + 17792) + w * 1056;   // [16][66] per wave
        const float rrf = pl[0 * 64 + lane], rif = pl[1 * 64 + lane];
        float pr = pl[2 * 64 + lane], pi = pl[3 * 64 + lane];   // w
        float br = pl[4 * 64 + lane], bi = pl[5 * 64 + lane];   // r^64
        int cc = w * 4;
        while (cc) {   // p = w * (r^64)^(4*wid)
            if (cc & 1) { float t_ = pr * br - pi * bi; pi = fmaf(pr, bi, pi * br); pr = t_; }
            float t2 = br * br - bi * bi; bi = 2.f * br * bi; br = t2;
            cc >>= 1;
        }
        const int jj = lane & 15, nq = lane >> 4;
        for (int qq = 0; qq < 16; ++qq) {
            #pragma unroll
            for (int j = 0; j < 16; ++j) {
                kl[j * 66 + lane] = pr;
                float t_ = pr * rrf - pi * rif; pi = fmaf(pr, rif, pi * rrf); pr = t_;
            }
            asm volatile("s_waitcnt lgkmcnt(0)" ::: "memory");
            float s0 = 0.f, s1 = 0.f;
            #pragma unroll
            for (int n = 0; n < 16; n += 4) {
                float2 a = *(const float2*)&kl[jj * 66 + nq * 16 + n];
                float2 b2 = *(const float2*)&kl[jj * 66 + nq * 16 + n + 2];
                s0 += a.x + a.y; s1 += b2.x + b2.y;
            }
            float s = s0 + s1;
            s += __shfl_xor(s, 16);
            s += __shfl_xor(s, 32);
            if (lane < 16) Kf[w * 256 + qq * 16 + jj] = s;
            asm volatile("s_waitcnt lgkmcnt(0)" ::: "memory");
        }
    }
    __syncthreads();

    {   // pack Kf -> G bf16 8 replicas: dword s*556+d = (K[2d+s], K[2d+1+s])
        unsigned int* Gd = (unsigned int*)smem;
        for (int t = tid; t < 4448; t += 256) {
            int s = t / 556;
            int d = t - s * 556;
            int idx0 = 2 * d + s;
            float k0 = (idx0 < 1024) ? Kf[idx0] : 0.f;
            float k1 = (idx0 + 1 < 1024) ? Kf[idx0 + 1] : 0.f;
            Gd[t] = (unsigned)f2bf(k0) | ((unsigned)f2bf(k1) << 16);
        }
    }
    if (tid < 8) { uint4 z = {0, 0, 0, 0}; ((uint4*)(smem + 36224))[tid] = z; }
    __syncthreads();

    {   // T14 write-late: cvt + store u regs -> [jc][b][72] bf16
        const int b2 = tid >> 5, t32 = tid & 31;
        #pragma unroll
        for (int g = 0; g < 8; ++g) {
            int s = t32 * 4 + g * 128;
            float4 v = ureg[g];
            unsigned short t0 = f2bf(v.x), t1 = f2bf(v.y), t2 = f2bf(v.z), t3 = f2bf(v.w);
            int jc = s >> 6, e = s & 63;
            *(uint2*)(smem + 17792 + jc * 1152 + b2 * 144 + e * 2) =
                make_uint2((unsigned)t0 | ((unsigned)t1 << 16),
                           (unsigned)t2 | ((unsigned)t3 << 16));
        }
    }
    __syncthreads();

    const int icg = (cg == 0) ? w : (cg == 1) ? 7 - w : (cg == 2) ? 8 + w : 15 - w;
    const int dmax = 15 - w;

    int aU = 17792 + icg * 1152 + b * 144 + q * 16;
    const int zl = 36224 + q * 16;

    const int sA = (7 - m) & 7;
    int baseH = sA * 2224 + (991 - m - sA + 8 * q) * 2;

    const f32x16 zacc = {};
    f32x16 acc0 = zacc, acc1 = zacc;

    short8 m2, m1, w0, w1, w2, w3;
#define LDA() { const char* pH = smem + baseH; \
        m2 = *(const short8*)(pH +   0); m1 = *(const short8*)(pH +  32); \
        w0 = *(const short8*)(pH +  64); w1 = *(const short8*)(pH +  96); \
        w2 = *(const short8*)(pH + 128); w3 = *(const short8*)(pH + 160); }
    LDA();

    for (int d = 0; d <= dmax; ++d) {
        const char* pb = smem + ((d <= icg) ? aU : zl);
        short8 b0 = *(const short8*)(pb +  0);
        short8 b1 = *(const short8*)(pb + 32);
        short8 b2 = *(const short8*)(pb + 64);
        short8 b3 = *(const short8*)(pb + 96);
        acc0 = __builtin_amdgcn_mfma_f32_32x32x16_bf16(w0, b0, acc0, 0, 0, 0);
        acc1 = __builtin_amdgcn_mfma_f32_32x32x16_bf16(m2, b0, acc1, 0, 0, 0);
        acc0 = __builtin_amdgcn_mfma_f32_32x32x16_bf16(w1, b1, acc0, 0, 0, 0);
        acc1 = __builtin_amdgcn_mfma_f32_32x32x16_bf16(m1, b1, acc1, 0, 0, 0);
        acc0 = __builtin_amdgcn_mfma_f32_32x32x16_bf16(w2, b2, acc0, 0, 0, 0);
        acc1 = __builtin_amdgcn_mfma_f32_32x32x16_bf16(w0, b2, acc1, 0, 0, 0);
        acc0 = __builtin_amdgcn_mfma_f32_32x32x16_bf16(w3, b3, acc0, 0, 0, 0);
        acc1 = __builtin_amdgcn_mfma_f32_32x32x16_bf16(w1, b3, acc1, 0, 0, 0);
        baseH -= 128; aU -= 1152;
        if (d < dmax) LDA();
    }
#undef LDA

    __syncthreads();   // G region dead -> Y bounce [16][8][68]

    #pragma unroll
    for (int mf = 0; mf < 2; ++mf) {
        const f32x16 ac = mf ? acc1 : acc0;
        #pragma unroll
        for (int rq = 0; rq < 4; ++rq) {
            const int row0 = mf * 32 + 8 * rq + 4 * q;
            uint2 uv2 = *(const uint2*)(smem + 17792 + icg * 1152 + b * 144 + row0 * 2);
            unsigned short us[4] = { (unsigned short)(uv2.x & 0xffff),
                                     (unsigned short)(uv2.x >> 16),
                                     (unsigned short)(uv2.y & 0xffff),
                                     (unsigned short)(uv2.y >> 16) };
            unsigned short oh[4];
            #pragma unroll
            for (int k = 0; k < 4; ++k) {
                float y = ac[rq * 4 + k] + Dh * bf2f(us[k]);
                float g = 0.5f * y * (1.0f + erff(y * 0.70710678118654752f));
                oh[k] = f2bf(g);
            }
            *(uint2*)(smem + icg * 1088 + b * 136 + row0 * 2) = pack4(oh);
        }
    }
    __syncthreads();
    {   // coalesced copy-out: Ybf[b][h][l]
        const int b2 = tid >> 5, t32 = tid & 31;
        unsigned short* dst = YbfH + ((size_t)(b2 * 512 + h)) * 1024;
        #pragma unroll
        for (int g = 0; g < 8; ++g) {
            int s = t32 * 4 + g * 128;
            int jc = s >> 6, e = s & 63;
            uint2 v = *(const uint2*)(smem + jc * 1088 + b2 * 136 + e * 2);
            *(uint2*)&dst[s] = v;
        }
    }
}

// W-hi-only bf16 MFMA GEMM with fused Y transpose; global staging is
// register-double-buffered so L2/L3 latency hides under MFMA of prior step.
__global__ __launch_bounds__(256) void k2_gemm(const unsigned short* __restrict__ WbfH,
                                               const unsigned short* __restrict__ Ybf,
                                               const float* __restrict__ conv_b,
                                               const float* __restrict__ dec_w,
                                               float* __restrict__ partial) {
    __shared__ unsigned short WTh[128][40];
    __shared__ unsigned short YT[128][44];
    __shared__ float red[4][64][20];
    const int tid = threadIdx.x, lane = tid & 63, wid = tid >> 6;
    const int b = blockIdx.z, oblk = blockIdx.y, lblk = blockIdx.x;
    const int o0 = oblk * 64, l0 = lblk * 128;
    const int fr = lane & 15, fq = lane >> 4;

    f32x4 acc[8][2] = {};

    const int srow = tid >> 1, skh = (tid & 1) * 16;
    const int grow = (srow < 64) ? (o0 + srow) : (512 + o0 + srow - 64);
    const size_t woff = (size_t)grow * 512 + skh;
    const int cp = tid & 15, lg = tid >> 4;
    const unsigned short* ysb = Ybf + ((size_t)(b * 512 + 2 * cp)) * 1024 + l0 + lg * 8;

    // prologue: prime c0 = 0
    uint4 wc0 = *(const uint4*)(WbfH + woff);
    uint4 wc1 = *(const uint4*)(WbfH + woff + 8);
    uint4 yc0 = *(const uint4*)(ysb);
    uint4 yc1 = *(const uint4*)(ysb + 1024);

    for (int c0 = 0; c0 < 512; c0 += 32) {
        __syncthreads();
        *(uint4*)&WTh[srow][skh]     = wc0;
        *(uint4*)&WTh[srow][skh + 8] = wc1;
        {
            const unsigned int* a = (const unsigned int*)&yc0;
            const unsigned int* c = (const unsigned int*)&yc1;
            #pragma unroll
            for (int t2 = 0; t2 < 4; ++t2) {
                unsigned int lo = (a[t2] & 0xffffu) | (c[t2] << 16);
                unsigned int hi = (a[t2] >> 16) | (c[t2] & 0xffff0000u);
                *(unsigned int*)&YT[lg * 8 + 2 * t2][2 * cp] = lo;
                *(unsigned int*)&YT[lg * 8 + 2 * t2 + 1][2 * cp] = hi;
            }
        }
        if (c0 + 32 < 512) {   // prefetch next step (latency hides under MFMA)
            wc0 = *(const uint4*)(WbfH + woff + c0 + 32);
            wc1 = *(const uint4*)(WbfH + woff + c0 + 40);
            const unsigned short* ysn = ysb + (size_t)(c0 + 32) * 1024;
            yc0 = *(const uint4*)(ysn);
            yc1 = *(const uint4*)(ysn + 1024);
        }
        __syncthreads();
        short8 b0h = ld16u((const char*)&YT[wid * 32 + fr][fq * 8]);
        short8 b1h = ld16u((const char*)&YT[wid * 32 + 16 + fr][fq * 8]);
        #pragma unroll
        for (int mf = 0; mf < 8; ++mf) {
            short8 ah = *(const short8*)&WTh[mf * 16 + fr][fq * 8];
            acc[mf][0] = __builtin_amdgcn_mfma_f32_16x16x32_bf16(ah, b0h, acc[mf][0], 0, 0, 0);
            acc[mf][1] = __builtin_amdgcn_mfma_f32_16x16x32_bf16(ah, b1h, acc[mf][1], 0, 0, 0);
        }
    }

    #pragma unroll
    for (int mf = 0; mf < 4; ++mf)
        #pragma unroll
        for (int j = 0; j < 4; ++j) {
            int ol = mf * 16 + fq * 4 + j;
            float ba = conv_b[o0 + ol];
            float bb = conv_b[512 + o0 + ol];
            float s = 0.f;
            #pragma unroll
            for (int nf = 0; nf < 2; ++nf) {
                float za = acc[mf][nf][j] + ba;
                float zb = acc[mf + 4][nf][j] + bb;
                s += za / (1.f + expf(-zb));
            }
            red[wid][ol][fr] = s;
        }
    __syncthreads();
    if (tid < 64) {
        float s = 0.f;
        #pragma unroll
        for (int w = 0; w < 4; ++w) {
            float4 r0 = *(const float4*)&red[w][tid][0];
            float4 r1 = *(const float4*)&red[w][tid][4];
            float4 r2 = *(const float4*)&red[w][tid][8];
            float4 r3 = *(const float4*)&red[w][tid][12];
            s += (r0.x + r0.y + r0.z + r0.w) + (r1.x + r1.y + r1.z + r1.w)
               + (r2.x + r2.y + r2.z + r2.w) + (r3.x + r3.y + r3.z + r3.w);
        }
        float val = s * dec_w[o0 + tid] * (1.0f / 1024.0f);
        #pragma unroll
        for (int off = 32; off; off >>= 1) val += __shfl_xor(val, off);
        if (tid == 0) partial[((b * 8) + oblk) * 8 + lblk] = val;
    }
}

__global__ void k3_final(const float* __restrict__ partial,
                         const float* __restrict__ dec_b,
                         float* __restrict__ out) {
    int b = threadIdx.x;
    if (b < Bm) {
        float s = dec_b[0];
        for (int i = 0; i < 64; ++i) s += partial[b * 64 + i];
        out[b] = s;
    }
}

extern "C" void kernel_launch(void* const* d_in, const int* in_sizes, int n_in,
                              void* d_out, int out_size, void* d_ws, size_t ws_size,
                              hipStream_t stream) {
    const float* u          = (const float*)d_in[0];
    const float* log_dt     = (const float*)d_in[1];
    const float* log_A_real = (const float*)d_in[2];
    const float* A_imag     = (const float*)d_in[3];
    const float* B_real     = (const float*)d_in[4];
    const float* B_imag     = (const float*)d_in[5];
    const float* C_real     = (const float*)d_in[6];
    const float* C_imag     = (const float*)d_in[7];
    const float* Dvec       = (const float*)d_in[8];
    const float* conv_w     = (const float*)d_in[9];
    const float* conv_b     = (const float*)d_in[10];
    const float* dec_w      = (const float*)d_in[11];
    const float* dec_b      = (const float*)d_in[12];

    char* base = (char*)d_ws;
    unsigned short* YbfH = (unsigned short*)base;                       // 8 MB
    unsigned short* Wh   = (unsigned short*)(base + 8388608);           // 1 MB
    float* partial       = (float*)(base + 9437184);                    // 2 KB
    float* out           = (float*)d_out;

    k_tconv<<<512, 256, 0, stream>>>(log_dt, log_A_real, A_imag, B_real, B_imag,
                                     C_real, C_imag, conv_w, u, Dvec, Wh, YbfH);
    k2_gemm<<<dim3(8, 8, 8), 256, 0, stream>>>(Wh, YbfH, conv_b, dec_w, partial);
    k3_final<<<1, 64, 0, stream>>>(partial, dec_b, out);
}